// Round 7
// baseline (407.150 us; speedup 1.0000x reference)
//
#include <hip/hip_runtime.h>
#include <hip/hip_bf16.h>
#include <cmath>

// ---------------------------------------------------------------------------
// GAT 2-layer forward.
//  - LDS-free MFMA GEMMs (A direct global->reg, B pre-transposed bf16).
//  - scores1 fused into GEMM1 (extra 16 cols via Wa = W1 @ blockdiag(a)),
//    Wa PRE-SCALED by log2e -> agg kernels use exp2f (bare v_exp_f32).
//  - h1 stored BIASED UINT8 (q+128) with per-row scale; agg1 unpacks with
//    v_cvt_f32_ubyte{0..3}, corrected by 128*sum(p*scale) in the epilogue.
//  - s1cc[node][head] = float2(score_h, scale): 64B-aligned records, ONE
//    8B load per edge-lane (no line straddle).
//  - agg1/agg2: two-level rotation-free 3x pipelines (index 1 rotation ahead).
//  - CSR build WITHOUT global atomics (bucketed counting sort P1..P4).
//  - Launch pipeline: gemm1 in 3 chunks under P1/P3/P4a; P4 split in half,
//    P4b co-launched with agg1 first half (independent node ranges).
//  - layer2: h2 row stride 48 ushorts, src-score f32 embedded at +40;
//    log_softmax fused into agg2.
// ---------------------------------------------------------------------------

typedef unsigned short ushortT;
typedef unsigned int uintT;
typedef unsigned char ucharT;
typedef __attribute__((ext_vector_type(8))) short short8;
typedef __attribute__((ext_vector_type(4))) float float4v;
typedef __attribute__((ext_vector_type(2))) float float2v;

#define LOG2E 1.4426950408889634f

static __device__ __forceinline__ float bflo(uintT u) {
    return __uint_as_float(u << 16);
}
static __device__ __forceinline__ float bfhi(uintT u) {
    return __uint_as_float(u & 0xffff0000u);
}
static __device__ __forceinline__ ushortT f2bf(float f) {
    __hip_bfloat16 h = __float2bfloat16(f);   // RNE
    return *reinterpret_cast<ushortT*>(&h);
}
static __device__ __forceinline__ uintT pk(float a, float b) {
    return (uintT)f2bf(a) | ((uintT)f2bf(b) << 16);
}
static __device__ __forceinline__ float ub(uintT u, int k) {   // unsigned byte k
    return (float)((u >> (8 * k)) & 0xffu);                    // -> v_cvt_f32_ubyteN
}
// leaky: e>=0 -> e ; e<0 -> 0.2e.  0.6e + 0.4|e| (2 VALU, abs = modifier)
static __device__ __forceinline__ float lrelu(float e) {
    return 0.6f * e + 0.4f * fabsf(e);
}

#define PREP_BLOCKS 184
#define EPB 4096              // edges per histogram/placement block

// ---------------- prep: transpose weights to bf16 + score matrix -----------
__global__ __launch_bounds__(256) void k_prep(const float* __restrict__ W1,
                                              const float* __restrict__ W2,
                                              const float* __restrict__ a1s,
                                              const float* __restrict__ a1d,
                                              ushortT* __restrict__ W1t,
                                              ushortT* __restrict__ W2t) {
    int t = blockIdx.x * 256 + threadIdx.x;
    if (t < 128 * 256) {
        int k = t >> 8, s = t & 255;
        int c = ((s & 15) << 4) | (s >> 4);
        W1t[s * 128 + k] = f2bf(W1[(size_t)k * 256 + c]);
    } else if (t < 128 * 256 + 48 * 256) {
        int q = t - 128 * 256;
        int k = q / 48, c = q - k * 48;
        W2t[c * 256 + k] = (c < 40) ? f2bf(W2[k * 40 + c]) : (ushortT)0;
    } else if (t < 128 * 256 + 48 * 256 + 2048) {
        int q = t - (128 * 256 + 48 * 256);
        int k = q >> 4, j = q & 15;
        int h = j & 7;
        const float* av = ((j < 8) ? a1s : a1d) + h * 32;
        const float* wr = W1 + (size_t)k * 256 + h * 32;
        float s = 0.f;
        #pragma unroll
        for (int c = 0; c < 32; ++c) s += wr[c] * av[c];
        W1t[(256 + j) * 128 + k] = f2bf(s * LOG2E);   // pre-scaled for exp2
    }
}

// ---------------- GEMM1 worker: x[16,128] @ W1 -> biased-u8 h1i + s1cc/s1d -
static __device__ __forceinline__ void dev_gemm1(int slab,
                                                 const float* __restrict__ A,
                                                 const ushortT* __restrict__ Bt,
                                                 ucharT* __restrict__ h1i,
                                                 float* __restrict__ s1cc,
                                                 float* __restrict__ s1d, int M) {
    int lane = threadIdx.x & 63;
    int r0 = slab * 16;
    if (r0 >= M) return;
    int n = lane & 15, q = lane >> 4;
    const float* arow = A + (size_t)(r0 + n) * 128 + q * 8;
    short8 af[4];
    #pragma unroll
    for (int s = 0; s < 4; ++s) {
        float4 v0 = *(const float4*)(arow + s * 32);
        float4 v1 = *(const float4*)(arow + s * 32 + 4);
        short8 a;
        a[0] = (short)f2bf(v0.x); a[1] = (short)f2bf(v0.y);
        a[2] = (short)f2bf(v0.z); a[3] = (short)f2bf(v0.w);
        a[4] = (short)f2bf(v1.x); a[5] = (short)f2bf(v1.y);
        a[6] = (short)f2bf(v1.z); a[7] = (short)f2bf(v1.w);
        af[s] = a;
    }
    float4v acc[17];
    #pragma unroll
    for (int j = 0; j < 17; ++j) acc[j] = (float4v){0.f, 0.f, 0.f, 0.f};
    #pragma unroll
    for (int s = 0; s < 4; ++s) {
        #pragma unroll
        for (int j = 0; j < 17; ++j) {
            short8 b = *(const short8*)(Bt + (size_t)(j * 16 + n) * 128 + s * 32 + q * 8);
            acc[j] = __builtin_amdgcn_mfma_f32_16x16x32_bf16(af[s], b, acc[j], 0, 0, 0);
        }
    }
    float am[4];
    #pragma unroll
    for (int r = 0; r < 4; ++r) {
        float m = 0.f;
        #pragma unroll
        for (int j = 0; j < 16; ++j) m = fmaxf(m, fabsf(acc[j][r]));
        am[r] = m;
    }
    #pragma unroll
    for (int off = 1; off < 16; off <<= 1) {
        #pragma unroll
        for (int r = 0; r < 4; ++r) am[r] = fmaxf(am[r], __shfl_xor(am[r], off, 64));
    }
    #pragma unroll
    for (int r = 0; r < 4; ++r) {
        int row = r0 + q * 4 + r;
        float m = am[r];
        float si = (m > 0.f) ? 127.f / m : 0.f;
        uintT wd[4];
        #pragma unroll
        for (int wq = 0; wq < 4; ++wq) {
            uintT p4 = 0;
            #pragma unroll
            for (int b = 0; b < 4; ++b) {
                int j = wq * 4 + b;
                int qv = (int)rintf(acc[j][r] * si) + 128;   // biased uint8
                p4 |= ((uintT)(qv & 0xff)) << (8 * b);
            }
            wd[wq] = p4;
        }
        uint4 o = make_uint4(wd[0], wd[1], wd[2], wd[3]);
        *(uint4*)(h1i + (size_t)row * 256 + n * 16) = o;
        float vv = acc[16][r];
        if (n < 8) {
            // (score_h, row scale) pair -> one 8B record per head
            *(float2*)(s1cc + ((size_t)row << 4) + n * 2) =
                make_float2(vv, m * (1.f / 127.f));
        } else {
            s1d[(size_t)row * 8 + (n - 8)] = vv;
        }
    }
}

// ---------------- P1: per-block LDS histogram over buckets (+ gemm chunk) --
__global__ __launch_bounds__(256) void k_cnt_g1(const int* __restrict__ ei, int E,
                                                int* __restrict__ counts, int nbuck,
                                                const float* __restrict__ A,
                                                const ushortT* __restrict__ Bt,
                                                ucharT* __restrict__ h1i,
                                                float* __restrict__ s1cc,
                                                float* __restrict__ s1d,
                                                int M, int nPrim, int slabBase) {
    if (blockIdx.x >= nPrim) {
        int wave = threadIdx.x >> 6;
        int slab = slabBase + (blockIdx.x - nPrim) * 4 + wave;
        dev_gemm1(slab, A, Bt, h1i, s1cc, s1d, M);
        return;
    }
    __shared__ int h[1024];
    int t = threadIdx.x;
    for (int i = t; i < nbuck; i += 256) h[i] = 0;
    __syncthreads();
    int base = blockIdx.x * EPB;
    #pragma unroll
    for (int r = 0; r < 4; ++r) {
        int i4 = base + (r * 256 + t) * 4;
        if (i4 + 3 < E) {
            int4 d = *(const int4*)(ei + E + i4);
            atomicAdd(&h[d.x >> 7], 1);
            atomicAdd(&h[d.y >> 7], 1);
            atomicAdd(&h[d.z >> 7], 1);
            atomicAdd(&h[d.w >> 7], 1);
        } else {
            for (int j = i4; j < E; ++j) atomicAdd(&h[ei[E + j] >> 7], 1);
        }
    }
    __syncthreads();
    int* crow = counts + (size_t)blockIdx.x * nbuck;
    for (int i = t; i < nbuck; i += 256) crow[i] = h[i];
}

// ---------------- P2: per-bucket exclusive scan across blocks --------------
__global__ __launch_bounds__(256) void k_scan_cols(int* __restrict__ counts,
                                                   int* __restrict__ totals,
                                                   int nb1, int nbuck) {
    __shared__ int wsum[4];
    int k = blockIdx.x;
    int t = threadIdx.x, lane = t & 63, wv = t >> 6;
    int e0 = 2 * t, e1 = 2 * t + 1;
    int v0 = (e0 < nb1) ? counts[(size_t)e0 * nbuck + k] : 0;
    int v1 = (e1 < nb1) ? counts[(size_t)e1 * nbuck + k] : 0;
    int s = v0 + v1;
    int incl = s;
    #pragma unroll
    for (int off = 1; off < 64; off <<= 1) {
        int u = __shfl_up(incl, off, 64);
        if (lane >= off) incl += u;
    }
    if (lane == 63) wsum[wv] = incl;
    __syncthreads();
    int add = 0;
    if (wv > 0) add += wsum[0];
    if (wv > 1) add += wsum[1];
    if (wv > 2) add += wsum[2];
    incl += add;
    int excl = incl - s;
    if (e0 < nb1) counts[(size_t)e0 * nbuck + k] = excl;
    if (e1 < nb1) counts[(size_t)e1 * nbuck + k] = excl + v0;
    if (t == 255) totals[k] = incl;
}

// ---------------- P3: bucket-contiguous placement (+ gemm chunk) -----------
__global__ __launch_bounds__(256) void k_place_g1(const int* __restrict__ ei, int E,
                                                  const int* __restrict__ counts,
                                                  const int* __restrict__ totals,
                                                  int* __restrict__ bstart,
                                                  uintT* __restrict__ tmp, int nbuck,
                                                  const float* __restrict__ A,
                                                  const ushortT* __restrict__ Bt,
                                                  ucharT* __restrict__ h1i,
                                                  float* __restrict__ s1cc,
                                                  float* __restrict__ s1d,
                                                  int M, int nPrim, int slabBase) {
    if (blockIdx.x >= nPrim) {
        int wave = threadIdx.x >> 6;
        int slab = slabBase + (blockIdx.x - nPrim) * 4 + wave;
        dev_gemm1(slab, A, Bt, h1i, s1cc, s1d, M);
        return;
    }
    __shared__ int st[1024];
    __shared__ int pos[1024];
    __shared__ int wsum[4];
    int t = threadIdx.x, lane = t & 63, wv = t >> 6;
    int b = blockIdx.x;
    int g[4];
    int s = 0;
    #pragma unroll
    for (int j = 0; j < 4; ++j) {
        int e = 4 * t + j;
        g[j] = (e < nbuck) ? totals[e] : 0;
        s += g[j];
    }
    int incl = s;
    #pragma unroll
    for (int off = 1; off < 64; off <<= 1) {
        int u = __shfl_up(incl, off, 64);
        if (lane >= off) incl += u;
    }
    if (lane == 63) wsum[wv] = incl;
    __syncthreads();
    int add = 0;
    if (wv > 0) add += wsum[0];
    if (wv > 1) add += wsum[1];
    if (wv > 2) add += wsum[2];
    int excl = incl + add - s;
    #pragma unroll
    for (int j = 0; j < 4; ++j) {
        int e = 4 * t + j;
        if (e < nbuck) st[e] = excl;
        excl += g[j];
    }
    __syncthreads();
    const int* crow = counts + (size_t)b * nbuck;
    for (int i = t; i < nbuck; i += 256) {
        int sv = st[i];
        pos[i] = sv + crow[i];
        if (b == 0) bstart[i] = sv;
    }
    __syncthreads();
    int base = b * EPB;
    #pragma unroll
    for (int r = 0; r < 4; ++r) {
        int i4 = base + (r * 256 + t) * 4;
        if (i4 + 3 < E) {
            int4 sv = *(const int4*)(ei + i4);
            int4 dv = *(const int4*)(ei + E + i4);
            int p0 = atomicAdd(&pos[dv.x >> 7], 1);
            tmp[p0] = (uintT)sv.x | (((uintT)dv.x & 127u) << 17);
            int p1 = atomicAdd(&pos[dv.y >> 7], 1);
            tmp[p1] = (uintT)sv.y | (((uintT)dv.y & 127u) << 17);
            int p2 = atomicAdd(&pos[dv.z >> 7], 1);
            tmp[p2] = (uintT)sv.z | (((uintT)dv.z & 127u) << 17);
            int p3 = atomicAdd(&pos[dv.w >> 7], 1);
            tmp[p3] = (uintT)sv.w | (((uintT)dv.w & 127u) << 17);
        } else {
            for (int j = i4; j < E; ++j) {
                int sj = ei[j], dj = ei[E + j];
                int p = atomicAdd(&pos[dj >> 7], 1);
                tmp[p] = (uintT)sj | (((uintT)dj & 127u) << 17);
            }
        }
    }
}

// ---------------- P4 worker: per-bucket CSR finalize ------------------------
static __device__ __forceinline__ void dev_csr(int k,
                                               const uintT* __restrict__ tmp,
                                               const int* __restrict__ bstart,
                                               const int* __restrict__ totals,
                                               int* __restrict__ rowptr,
                                               int* __restrict__ csr_src,
                                               int N, int* cnt, int* cur,
                                               int* wtot) {
    int t = threadIdx.x;
    int nodeBase = k << 7;
    int nn = N - nodeBase;
    if (nn > 128) nn = 128;
    int myStart = bstart[k];
    int myCount = totals[k];
    int csrBase = myStart + nodeBase;   // + self loops of preceding nodes
    if (t < 128) cnt[t] = 0;
    __syncthreads();
    for (int i = t; i < myCount; i += 256) {
        uintT p = tmp[myStart + i];
        atomicAdd(&cnt[p >> 17], 1);
    }
    __syncthreads();
    int dseg = 0, incl = 0;
    if (t < 128) {
        dseg = (t < nn) ? cnt[t] + 1 : 0;   // +1 self loop
        incl = dseg;
        #pragma unroll
        for (int off = 1; off < 64; off <<= 1) {
            int u = __shfl_up(incl, off, 64);
            if ((t & 63) >= off) incl += u;
        }
        if (t == 63) *wtot = incl;
    }
    __syncthreads();
    if (t < nn) {
        int excl = incl - dseg + ((t >= 64) ? *wtot : 0);
        int rp = csrBase + excl;
        int node = nodeBase + t;
        rowptr[node + 1] = rp + dseg;
        csr_src[rp] = node;              // self loop first
        cur[t] = rp + 1;
    }
    if (k == 0 && t == 0) rowptr[0] = 0;
    __syncthreads();
    for (int i = t; i < myCount; i += 256) {
        uintT p = tmp[myStart + i];
        int ld = p >> 17;
        int q = atomicAdd(&cur[ld], 1);
        csr_src[q] = (int)(p & 0x1FFFFu);
    }
}

// ---------------- P4a: buckets [0, nPrim) (+ gemm chunk) -------------------
__global__ __launch_bounds__(256) void k_csr_g1(const uintT* __restrict__ tmp,
                                                const int* __restrict__ bstart,
                                                const int* __restrict__ totals,
                                                int* __restrict__ rowptr,
                                                int* __restrict__ csr_src,
                                                int N,
                                                const float* __restrict__ A,
                                                const ushortT* __restrict__ Bt,
                                                ucharT* __restrict__ h1i,
                                                float* __restrict__ s1cc,
                                                float* __restrict__ s1d,
                                                int M, int nPrim, int slabBase) {
    __shared__ int cnt[128];
    __shared__ int cur[128];
    __shared__ int wtot;
    if (blockIdx.x >= nPrim) {
        int wave = threadIdx.x >> 6;
        int slab = slabBase + (blockIdx.x - nPrim) * 4 + wave;
        dev_gemm1(slab, A, Bt, h1i, s1cc, s1d, M);
        return;
    }
    dev_csr(blockIdx.x, tmp, bstart, totals, rowptr, csr_src, N, cnt, cur, &wtot);
}

// ---------------- layer-1 aggregation worker --------------------------------
// 16 ch/lane (uint4), 16 lanes/edge, 4 edges/wave; rotation-free 3x unroll;
// two-level pipeline: index prefetched 1 rotation ahead of value gathers.
struct Edge1 {
    float2 svc;       // (score_head, row scale)
    uint4 v;
    int si;
};

static __device__ __forceinline__ void ldi1(Edge1& S, int j, int endm1,
                                            const int* __restrict__ csr_src) {
    int jj = j < endm1 ? j : endm1;
    S.si = csr_src[jj];
}

static __device__ __forceinline__ void ldv1(Edge1& S, int j, int end,
                                            const float2* __restrict__ sc2,
                                            const ucharT* __restrict__ hb, int head) {
    if (j < end) {
        int s = S.si;
        S.svc = sc2[((size_t)s << 3) + head];
        S.v = *(const uint4*)(hb + ((size_t)s << 8));
    }
}

static __device__ __forceinline__ void ac1(const Edge1& S, float sdn,
                                           float2v* A, float& l, float& sps) {
    float p = exp2f(lrelu(S.svc.x + sdn));   // scores pre-scaled by log2e
    l += p;
    float ps = p * S.svc.y;
    sps += ps;
    float2v p2 = {ps, ps};
    uintT w;
    w = S.v.x;
    A[0] += p2 * (float2v){ub(w, 0), ub(w, 1)};
    A[1] += p2 * (float2v){ub(w, 2), ub(w, 3)};
    w = S.v.y;
    A[2] += p2 * (float2v){ub(w, 0), ub(w, 1)};
    A[3] += p2 * (float2v){ub(w, 2), ub(w, 3)};
    w = S.v.z;
    A[4] += p2 * (float2v){ub(w, 0), ub(w, 1)};
    A[5] += p2 * (float2v){ub(w, 2), ub(w, 3)};
    w = S.v.w;
    A[6] += p2 * (float2v){ub(w, 0), ub(w, 1)};
    A[7] += p2 * (float2v){ub(w, 2), ub(w, 3)};
}

static __device__ __forceinline__ void dev_agg1(int n,
                                                const ucharT* __restrict__ h1i,
                                                const float* __restrict__ s1cc,
                                                const float* __restrict__ s1d,
                                                const int* __restrict__ rowptr,
                                                const int* __restrict__ csr_src,
                                                const float* __restrict__ b1,
                                                ushortT* __restrict__ out1) {
    int lane = threadIdx.x & 63;
    int g = lane >> 4;           // 4 edge slots
    int cl = lane & 15;          // 16 channels each
    int head = cl >> 1;
    int beg = rowptr[n], end = rowptr[n + 1];
    float sdn = s1d[(size_t)n * 8 + head];
    const ucharT* hb = h1i + cl * 16;
    const float2* sc2 = (const float2*)s1cc;
    float2v A[8];
    #pragma unroll
    for (int k = 0; k < 8; ++k) A[k] = (float2v){0.f, 0.f};
    float l = 0.f, sps = 0.f;
    int i0 = beg + g;
    if (i0 < end) {
        int endm1 = end - 1;
        Edge1 S0, S1, S2;
        S0.svc = S1.svc = S2.svc = make_float2(0.f, 0.f);
        S0.v = S1.v = S2.v = make_uint4(0u, 0u, 0u, 0u);
        ldi1(S0, i0, endm1, csr_src);
        ldi1(S1, i0 + 4, endm1, csr_src);
        ldi1(S2, i0 + 8, endm1, csr_src);
        ldv1(S0, i0, end, sc2, hb, head);
        ldv1(S1, i0 + 4, end, sc2, hb, head);
        ldv1(S2, i0 + 8, end, sc2, hb, head);
        ldi1(S0, i0 + 12, endm1, csr_src);
        ldi1(S1, i0 + 16, endm1, csr_src);
        ldi1(S2, i0 + 20, endm1, csr_src);
        for (int idx = i0; idx < end; idx += 12) {
            ac1(S0, sdn, A, l, sps);
            ldv1(S0, idx + 12, end, sc2, hb, head);
            ldi1(S0, idx + 24, endm1, csr_src);
            if (idx + 4 < end) {
                ac1(S1, sdn, A, l, sps);
                ldv1(S1, idx + 16, end, sc2, hb, head);
                ldi1(S1, idx + 28, endm1, csr_src);
            }
            if (idx + 8 < end) {
                ac1(S2, sdn, A, l, sps);
                ldv1(S2, idx + 20, end, sc2, hb, head);
                ldi1(S2, idx + 32, endm1, csr_src);
            }
        }
    }
    // reduce across the 4 edge-slot groups (lanes differing in bits 4,5)
    #pragma unroll
    for (int off = 16; off < 64; off <<= 1) {
        l += __shfl_xor(l, off, 64);
        sps += __shfl_xor(sps, off, 64);
        #pragma unroll
        for (int k = 0; k < 8; ++k) {
            A[k].x += __shfl_xor(A[k].x, off, 64);
            A[k].y += __shfl_xor(A[k].y, off, 64);
        }
    }
    if (g == 0) {
        float inv = 1.f / l;
        float adj = 128.f * sps;            // undo the uint8 bias
        const float4 bb0 = *(const float4*)(b1 + cl * 16);
        const float4 bb1 = *(const float4*)(b1 + cl * 16 + 4);
        const float4 bb2 = *(const float4*)(b1 + cl * 16 + 8);
        const float4 bb3 = *(const float4*)(b1 + cl * 16 + 12);
        float bbf[16] = {bb0.x, bb0.y, bb0.z, bb0.w, bb1.x, bb1.y, bb1.z, bb1.w,
                         bb2.x, bb2.y, bb2.z, bb2.w, bb3.x, bb3.y, bb3.z, bb3.w};
        uintT o[8];
        #pragma unroll
        for (int k = 0; k < 8; ++k) {
            float x0 = fmaxf((A[k].x - adj) * inv + bbf[2 * k], 0.f);
            float x1 = fmaxf((A[k].y - adj) * inv + bbf[2 * k + 1], 0.f);
            o[k] = pk(x0, x1);
        }
        *(uint4*)(out1 + (size_t)n * 256 + cl * 16) =
            make_uint4(o[0], o[1], o[2], o[3]);
        *(uint4*)(out1 + (size_t)n * 256 + cl * 16 + 8) =
            make_uint4(o[4], o[5], o[6], o[7]);
    }
}

// ---------------- fused: P4b (buckets >= halfB) ∥ agg1 nodes [0, H) --------
__global__ __launch_bounds__(256) void k_csr_agg1(const uintT* __restrict__ tmp,
                                                  const int* __restrict__ bstart,
                                                  const int* __restrict__ totals,
                                                  int* __restrict__ rowptr,
                                                  int* __restrict__ csr_src,
                                                  int N, int halfB, int nP4,
                                                  const ucharT* __restrict__ h1i,
                                                  const float* __restrict__ s1cc,
                                                  const float* __restrict__ s1d,
                                                  const float* __restrict__ b1,
                                                  ushortT* __restrict__ out1, int H) {
    __shared__ int cnt[128];
    __shared__ int cur[128];
    __shared__ int wtot;
    if (blockIdx.x < nP4) {
        dev_csr(halfB + blockIdx.x, tmp, bstart, totals, rowptr, csr_src, N,
                cnt, cur, &wtot);
        return;
    }
    int n = (blockIdx.x - nP4) * 4 + (threadIdx.x >> 6);
    if (n >= H) return;
    dev_agg1(n, h1i, s1cc, s1d, rowptr, csr_src, b1, out1);
}

// ---------------- agg1 tail: nodes [H, N) ----------------------------------
__global__ __launch_bounds__(256) void k_agg1(const ucharT* __restrict__ h1i,
                                              const float* __restrict__ s1cc,
                                              const float* __restrict__ s1d,
                                              const int* __restrict__ rowptr,
                                              const int* __restrict__ csr_src,
                                              const float* __restrict__ b1,
                                              ushortT* __restrict__ out1,
                                              int base, int N) {
    int n = base + blockIdx.x * 4 + (threadIdx.x >> 6);
    if (n >= N) return;
    dev_agg1(n, h1i, s1cc, s1d, rowptr, csr_src, b1, out1);
}

// ---------------- GEMM2: out1b[M,256] @ W2 -> h2 rows (stride 48) + s2d ----
// H2 row: cols 0..39 bf16, src-score f32 (pre-scaled) embedded at +40.
__global__ __launch_bounds__(256) void k_gemm2(const ushortT* __restrict__ X,
                                               const ushortT* __restrict__ Bt,
                                               const float* __restrict__ a2s,
                                               const float* __restrict__ a2d,
                                               ushortT* __restrict__ H2,
                                               float* __restrict__ s2d, int M) {
    int lane = threadIdx.x & 63, wave = threadIdx.x >> 6;
    int slab = blockIdx.x * 4 + wave;
    int r0 = slab * 16;
    if (r0 >= M) return;
    int n = lane & 15, q = lane >> 4;
    const ushortT* xrow = X + (size_t)(r0 + n) * 256 + q * 8;
    float4v acc[3];
    #pragma unroll
    for (int j = 0; j < 3; ++j) acc[j] = (float4v){0.f, 0.f, 0.f, 0.f};
    #pragma unroll
    for (int s = 0; s < 8; ++s) {
        short8 a = *(const short8*)(xrow + s * 32);
        #pragma unroll
        for (int j = 0; j < 3; ++j) {
            short8 b = *(const short8*)(Bt + (size_t)(j * 16 + n) * 256 + s * 32 + q * 8);
            acc[j] = __builtin_amdgcn_mfma_f32_16x16x32_bf16(a, b, acc[j], 0, 0, 0);
        }
    }
    float asv[3], adv[3];
    #pragma unroll
    for (int j = 0; j < 3; ++j) {
        int col = j * 16 + n;
        asv[j] = (col < 40) ? a2s[col] * LOG2E : 0.f;
        adv[j] = (col < 40) ? a2d[col] * LOG2E : 0.f;
    }
    float us[4], ud[4];
    #pragma unroll
    for (int r = 0; r < 4; ++r) {
        us[r] = acc[0][r] * asv[0] + acc[1][r] * asv[1] + acc[2][r] * asv[2];
        ud[r] = acc[0][r] * adv[0] + acc[1][r] * adv[1] + acc[2][r] * adv[2];
    }
    #pragma unroll
    for (int off = 1; off < 16; off <<= 1) {
        #pragma unroll
        for (int r = 0; r < 4; ++r) {
            us[r] += __shfl_xor(us[r], off, 64);
            ud[r] += __shfl_xor(ud[r], off, 64);
        }
    }
    #pragma unroll
    for (int j = 0; j < 3; ++j) {
        int col = j * 16 + n;
        if (col < 40) {
            #pragma unroll
            for (int r = 0; r < 4; ++r)
                H2[(size_t)(r0 + q * 4 + r) * 48 + col] = f2bf(acc[j][r]);
        }
    }
    if (n == 0) {
        #pragma unroll
        for (int r = 0; r < 4; ++r) {
            int row = r0 + q * 4 + r;
            *(float*)(H2 + (size_t)row * 48 + 40) = us[r];
            s2d[row] = ud[r];
        }
    }
}

// ---------------- layer-2 aggregation + log_softmax ------------------------
// 6 edge slots x 10 ch-lanes; two-level 3x-unrolled pipeline.
struct Edge2 {
    float sv;
    uint2 v;
    int si;
};

static __device__ __forceinline__ void ldi2(Edge2& S, int j, int endm1,
                                            const int* __restrict__ csr_src) {
    int jj = j < endm1 ? j : endm1;
    S.si = csr_src[jj];
}

static __device__ __forceinline__ void ldv2(Edge2& S, int j, int end,
                                            const ushortT* __restrict__ h2, int cl) {
    if (j < end) {
        int s = S.si;
        const ushortT* hr = h2 + (size_t)s * 48;
        S.v = *(const uint2*)(hr + cl * 4);
        S.sv = *(const float*)(hr + 40);
    }
}

static __device__ __forceinline__ void ac2(const Edge2& S, float sdn,
                                           float2v& A01, float2v& A23, float& l) {
    float p = exp2f(lrelu(S.sv + sdn));   // pre-scaled scores
    l += p;
    float2v p2 = {p, p};
    A01 += p2 * (float2v){bflo(S.v.x), bfhi(S.v.x)};
    A23 += p2 * (float2v){bflo(S.v.y), bfhi(S.v.y)};
}

__global__ __launch_bounds__(256) void k_agg2lsm(const ushortT* __restrict__ h2,
                                                 const float* __restrict__ sd,
                                                 const int* __restrict__ rowptr,
                                                 const int* __restrict__ csr_src,
                                                 const float* __restrict__ b2,
                                                 float* __restrict__ out, int N) {
    int lane = threadIdx.x & 63;
    int wid = threadIdx.x >> 6;
    int n = blockIdx.x * 4 + wid;
    if (n >= N) return;
    int el = lane / 10;
    int cl = lane - el * 10;
    int beg = rowptr[n], end = rowptr[n + 1];
    float sdn = sd[n];
    float2v A01 = (float2v){0.f, 0.f}, A23 = (float2v){0.f, 0.f};
    float l = 0.f;
    if (el < 6) {
        int i0 = beg + el;
        if (i0 < end) {
            int endm1 = end - 1;
            Edge2 S0, S1, S2;
            S0.sv = S1.sv = S2.sv = 0.f;
            S0.v = S1.v = S2.v = make_uint2(0u, 0u);
            ldi2(S0, i0, endm1, csr_src);
            ldi2(S1, i0 + 6, endm1, csr_src);
            ldi2(S2, i0 + 12, endm1, csr_src);
            ldv2(S0, i0, end, h2, cl);
            ldv2(S1, i0 + 6, end, h2, cl);
            ldv2(S2, i0 + 12, end, h2, cl);
            ldi2(S0, i0 + 18, endm1, csr_src);
            ldi2(S1, i0 + 24, endm1, csr_src);
            ldi2(S2, i0 + 30, endm1, csr_src);
            for (int idx = i0; idx < end; idx += 18) {
                ac2(S0, sdn, A01, A23, l);
                ldv2(S0, idx + 18, end, h2, cl);
                ldi2(S0, idx + 36, endm1, csr_src);
                if (idx + 6 < end) {
                    ac2(S1, sdn, A01, A23, l);
                    ldv2(S1, idx + 24, end, h2, cl);
                    ldi2(S1, idx + 42, endm1, csr_src);
                }
                if (idx + 12 < end) {
                    ac2(S2, sdn, A01, A23, l);
                    ldv2(S2, idx + 30, end, h2, cl);
                    ldi2(S2, idx + 48, endm1, csr_src);
                }
            }
        }
    }
    float a0 = A01.x, a1 = A01.y, a2 = A23.x, a3 = A23.y;
    // reduce the 6 slots into lanes 0..9
    float t0 = 0.f, t1 = 0.f, t2 = 0.f, t3 = 0.f, lt = 0.f;
    #pragma unroll
    for (int k = 0; k < 6; ++k) {
        int sl = cl + 10 * k;
        t0 += __shfl(a0, sl, 64);
        t1 += __shfl(a1, sl, 64);
        t2 += __shfl(a2, sl, 64);
        t3 += __shfl(a3, sl, 64);
        if (cl == 0) lt += __shfl(l, sl, 64);
    }
    lt = __shfl(lt, 0, 64);
    float inv = 1.f / lt;
    float o0 = t0 * inv + b2[cl * 4 + 0];
    float o1 = t1 * inv + b2[cl * 4 + 1];
    float o2 = t2 * inv + b2[cl * 4 + 2];
    float o3 = t3 * inv + b2[cl * 4 + 3];
    float lm = (lane < 10) ? fmaxf(fmaxf(o0, o1), fmaxf(o2, o3)) : -INFINITY;
    #pragma unroll
    for (int off = 32; off; off >>= 1) lm = fmaxf(lm, __shfl_xor(lm, off, 64));
    float le = (lane < 10)
        ? __expf(o0 - lm) + __expf(o1 - lm) + __expf(o2 - lm) + __expf(o3 - lm)
        : 0.f;
    #pragma unroll
    for (int off = 32; off; off >>= 1) le += __shfl_xor(le, off, 64);
    float ls = lm + logf(le);
    if (lane < 10) {
        float4 w = make_float4(o0 - ls, o1 - ls, o2 - ls, o3 - ls);
        *(float4*)(out + (size_t)n * 40 + cl * 4) = w;
    }
}

// ---------------------------------------------------------------------------
extern "C" void kernel_launch(void* const* d_in, const int* in_sizes, int n_in,
                              void* d_out, int out_size, void* d_ws, size_t ws_size,
                              hipStream_t stream) {
    const float* x   = (const float*)d_in[0];
    const int*   ei  = (const int*)d_in[1];
    const float* W1  = (const float*)d_in[2];
    const float* a1s = (const float*)d_in[3];
    const float* a1d = (const float*)d_in[4];
    const float* b1  = (const float*)d_in[5];
    const float* W2  = (const float*)d_in[6];
    const float* a2s = (const float*)d_in[7];
    const float* a2d = (const float*)d_in[8];
    const float* b2  = (const float*)d_in[9];
    float* out = (float*)d_out;

    const int N = in_sizes[0] / 128;   // 100000
    const int E = in_sizes[1] / 2;     // 1600000
    const int ET = E + N;
    const int NBUCK = (N + 127) >> 7;              // 782
    const int NB1 = (E + EPB - 1) / EPB;           // 391

    // ---- workspace layout ----
    char* w = (char*)d_ws;
    ucharT* h1i = (ucharT*)w;                             // N*256 u8 (25.6 MB)
    ushortT* out1b = (ushortT*)(w + (size_t)N * 256);     // N*256 bf16 (51.2 MB)
    int* i_row = (int*)(w + (size_t)N * 768);             // N+16 ints
    float* s1cc = (float*)(w + (size_t)N * 768 + ((size_t)N + 16) * 4); // N*16 f32
    float* s1d = s1cc + (size_t)N * 16;                   // N*8 f32
    int* i_cnt = (int*)(s1d + (size_t)N * 8);             // NB1*NBUCK
    int* i_tot = i_cnt + (size_t)NB1 * NBUCK;             // NBUCK+2
    int* i_bst = i_tot + NBUCK + 2;                       // NBUCK+2
    uintT* i_tmp = (uintT*)(i_bst + NBUCK + 2);           // E packed pairs
    int* i_csr = (int*)(i_tmp + E);                       // ET ints
    ushortT* W1t = (ushortT*)(i_csr + ET);                // 272*128 bf16
    ushortT* W2t = W1t + 272 * 128;                       // 48*256 bf16
    // layer-2 overlays (dead after agg1 / P3):
    //   h2b (N*48 ushort = N*96 B) over s1cc+s1d (N*64 + N*32 = N*96 B, exact)
    //   s2d (N f32) over i_cnt (dead after P3; P4 uses bstart/totals only)
    ushortT* h2b = (ushortT*)s1cc;
    float* s2d = (float*)i_cnt;

    const int nb4 = (N + 3) / 4;
    const int nbG = (N / 16 + 3) / 4;            // gemm blocks (4 waves x 16 rows)
    const int CH  = (nbG + 2) / 3;               // gemm1 chunk (blocks)
    const int halfB = NBUCK >> 1;                // 391
    const int H = halfB << 7;                    // 50048 nodes in first half
    const int nP4b = NBUCK - halfB;              // 391

    // ---- L0: weight prep ----
    k_prep<<<PREP_BLOCKS, 256, 0, stream>>>(W1, W2, a1s, a1d, W1t, W2t);
    // ---- P1: bucket histogram ∥ gemm1 chunk 0 ----
    k_cnt_g1<<<NB1 + CH, 256, 0, stream>>>(ei, E, i_cnt, NBUCK,
                                           x, W1t, h1i, s1cc, s1d,
                                           N, NB1, 0);
    // ---- P2: per-bucket scan across blocks ----
    k_scan_cols<<<NBUCK, 256, 0, stream>>>(i_cnt, i_tot, NB1, NBUCK);
    // ---- P3: bucket-contiguous placement ∥ gemm1 chunk 1 ----
    k_place_g1<<<NB1 + CH, 256, 0, stream>>>(ei, E, i_cnt, i_tot, i_bst, i_tmp, NBUCK,
                                             x, W1t, h1i, s1cc, s1d,
                                             N, NB1, CH * 4);
    // ---- P4a: CSR finalize buckets [0, halfB) ∥ gemm1 chunk 2 ----
    k_csr_g1<<<halfB + CH, 256, 0, stream>>>(i_tmp, i_bst, i_tot, i_row, i_csr, N,
                                             x, W1t, h1i, s1cc, s1d,
                                             N, halfB, CH * 8);
    // ---- P4b ∥ agg1 nodes [0, H) ----
    k_csr_agg1<<<nP4b + H / 4, 256, 0, stream>>>(i_tmp, i_bst, i_tot, i_row, i_csr,
                                                 N, halfB, nP4b,
                                                 h1i, s1cc, s1d, b1, out1b, H);
    // ---- agg1 tail: nodes [H, N) ----
    k_agg1<<<(N - H + 3) / 4, 256, 0, stream>>>(h1i, s1cc, s1d, i_row, i_csr, b1,
                                                out1b, H, N);

    // ---- layer 2 ----
    k_gemm2<<<nbG, 256, 0, stream>>>(out1b, W2t, a2s, a2d, h2b, s2d, N);
    k_agg2lsm<<<nb4, 256, 0, stream>>>(h2b, s2d, i_row, i_csr, b2, out, N);
}

// Round 8
// 398.804 us; speedup vs baseline: 1.0209x; 1.0209x over previous
//
#include <hip/hip_runtime.h>
#include <hip/hip_bf16.h>
#include <cmath>

// ---------------------------------------------------------------------------
// GAT 2-layer forward.
//  - LDS-free MFMA GEMMs (A direct global->reg, B pre-transposed bf16).
//  - scores1 fused into GEMM1 (extra 16 cols via Wa = W1 @ blockdiag(a)),
//    Wa PRE-SCALED by log2e -> agg kernels use exp2f (bare v_exp_f32).
//  - h1 stored BIASED UINT8 (q+128) with per-row scale; agg1 unpacks with
//    v_cvt_f32_ubyte{0..3}, corrected by 128*sum(p*scale) in the epilogue.
//  - s1cc[node][head] = float2(score_h, scale): 64B-aligned records.
//  - agg1: TWO NODES PER WAVE (32-lane halves), 2 slots x 16 ch-lanes each;
//    reduce = single xor-16 step (18 ops, was 36).
//  - agg2: staged slot-fold reduce (15 bpermutes/node, was 31).
//  - Two-level rotation-free 3x pipelines (index 1 rotation ahead).
//  - CSR build WITHOUT global atomics (bucketed counting sort P1..P4);
//    gemm1 in 3 chunks under P1/P3/P4a; P4b co-launched with agg1 half 1.
//  - layer2: h2 row stride 48 ushorts, src-score f32 embedded at +40;
//    log_softmax fused into agg2.
// ---------------------------------------------------------------------------

typedef unsigned short ushortT;
typedef unsigned int uintT;
typedef unsigned char ucharT;
typedef __attribute__((ext_vector_type(8))) short short8;
typedef __attribute__((ext_vector_type(4))) float float4v;
typedef __attribute__((ext_vector_type(2))) float float2v;

#define LOG2E 1.4426950408889634f

static __device__ __forceinline__ float bflo(uintT u) {
    return __uint_as_float(u << 16);
}
static __device__ __forceinline__ float bfhi(uintT u) {
    return __uint_as_float(u & 0xffff0000u);
}
static __device__ __forceinline__ ushortT f2bf(float f) {
    __hip_bfloat16 h = __float2bfloat16(f);   // RNE
    return *reinterpret_cast<ushortT*>(&h);
}
static __device__ __forceinline__ uintT pk(float a, float b) {
    return (uintT)f2bf(a) | ((uintT)f2bf(b) << 16);
}
static __device__ __forceinline__ float ub(uintT u, int k) {   // unsigned byte k
    return (float)((u >> (8 * k)) & 0xffu);                    // -> v_cvt_f32_ubyteN
}
// leaky: e>=0 -> e ; e<0 -> 0.2e.  0.6e + 0.4|e| (2 VALU, abs = modifier)
static __device__ __forceinline__ float lrelu(float e) {
    return 0.6f * e + 0.4f * fabsf(e);
}

#define PREP_BLOCKS 184
#define EPB 4096              // edges per histogram/placement block

// ---------------- prep: transpose weights to bf16 + score matrix -----------
__global__ __launch_bounds__(256) void k_prep(const float* __restrict__ W1,
                                              const float* __restrict__ W2,
                                              const float* __restrict__ a1s,
                                              const float* __restrict__ a1d,
                                              ushortT* __restrict__ W1t,
                                              ushortT* __restrict__ W2t) {
    int t = blockIdx.x * 256 + threadIdx.x;
    if (t < 128 * 256) {
        int k = t >> 8, s = t & 255;
        int c = ((s & 15) << 4) | (s >> 4);
        W1t[s * 128 + k] = f2bf(W1[(size_t)k * 256 + c]);
    } else if (t < 128 * 256 + 48 * 256) {
        int q = t - 128 * 256;
        int k = q / 48, c = q - k * 48;
        W2t[c * 256 + k] = (c < 40) ? f2bf(W2[k * 40 + c]) : (ushortT)0;
    } else if (t < 128 * 256 + 48 * 256 + 2048) {
        int q = t - (128 * 256 + 48 * 256);
        int k = q >> 4, j = q & 15;
        int h = j & 7;
        const float* av = ((j < 8) ? a1s : a1d) + h * 32;
        const float* wr = W1 + (size_t)k * 256 + h * 32;
        float s = 0.f;
        #pragma unroll
        for (int c = 0; c < 32; ++c) s += wr[c] * av[c];
        W1t[(256 + j) * 128 + k] = f2bf(s * LOG2E);   // pre-scaled for exp2
    }
}

// ---------------- GEMM1 worker: x[16,128] @ W1 -> biased-u8 h1i + s1cc/s1d -
static __device__ __forceinline__ void dev_gemm1(int slab,
                                                 const float* __restrict__ A,
                                                 const ushortT* __restrict__ Bt,
                                                 ucharT* __restrict__ h1i,
                                                 float* __restrict__ s1cc,
                                                 float* __restrict__ s1d, int M) {
    int lane = threadIdx.x & 63;
    int r0 = slab * 16;
    if (r0 >= M) return;
    int n = lane & 15, q = lane >> 4;
    const float* arow = A + (size_t)(r0 + n) * 128 + q * 8;
    short8 af[4];
    #pragma unroll
    for (int s = 0; s < 4; ++s) {
        float4 v0 = *(const float4*)(arow + s * 32);
        float4 v1 = *(const float4*)(arow + s * 32 + 4);
        short8 a;
        a[0] = (short)f2bf(v0.x); a[1] = (short)f2bf(v0.y);
        a[2] = (short)f2bf(v0.z); a[3] = (short)f2bf(v0.w);
        a[4] = (short)f2bf(v1.x); a[5] = (short)f2bf(v1.y);
        a[6] = (short)f2bf(v1.z); a[7] = (short)f2bf(v1.w);
        af[s] = a;
    }
    float4v acc[17];
    #pragma unroll
    for (int j = 0; j < 17; ++j) acc[j] = (float4v){0.f, 0.f, 0.f, 0.f};
    #pragma unroll
    for (int s = 0; s < 4; ++s) {
        #pragma unroll
        for (int j = 0; j < 17; ++j) {
            short8 b = *(const short8*)(Bt + (size_t)(j * 16 + n) * 128 + s * 32 + q * 8);
            acc[j] = __builtin_amdgcn_mfma_f32_16x16x32_bf16(af[s], b, acc[j], 0, 0, 0);
        }
    }
    float am[4];
    #pragma unroll
    for (int r = 0; r < 4; ++r) {
        float m = 0.f;
        #pragma unroll
        for (int j = 0; j < 16; ++j) m = fmaxf(m, fabsf(acc[j][r]));
        am[r] = m;
    }
    #pragma unroll
    for (int off = 1; off < 16; off <<= 1) {
        #pragma unroll
        for (int r = 0; r < 4; ++r) am[r] = fmaxf(am[r], __shfl_xor(am[r], off, 64));
    }
    #pragma unroll
    for (int r = 0; r < 4; ++r) {
        int row = r0 + q * 4 + r;
        float m = am[r];
        float si = (m > 0.f) ? 127.f / m : 0.f;
        uintT wd[4];
        #pragma unroll
        for (int wq = 0; wq < 4; ++wq) {
            uintT p4 = 0;
            #pragma unroll
            for (int b = 0; b < 4; ++b) {
                int j = wq * 4 + b;
                int qv = (int)rintf(acc[j][r] * si) + 128;   // biased uint8
                p4 |= ((uintT)(qv & 0xff)) << (8 * b);
            }
            wd[wq] = p4;
        }
        uint4 o = make_uint4(wd[0], wd[1], wd[2], wd[3]);
        *(uint4*)(h1i + (size_t)row * 256 + n * 16) = o;
        float vv = acc[16][r];
        if (n < 8) {
            *(float2*)(s1cc + ((size_t)row << 4) + n * 2) =
                make_float2(vv, m * (1.f / 127.f));
        } else {
            s1d[(size_t)row * 8 + (n - 8)] = vv;
        }
    }
}

// ---------------- P1: per-block LDS histogram over buckets (+ gemm chunk) --
__global__ __launch_bounds__(256) void k_cnt_g1(const int* __restrict__ ei, int E,
                                                int* __restrict__ counts, int nbuck,
                                                const float* __restrict__ A,
                                                const ushortT* __restrict__ Bt,
                                                ucharT* __restrict__ h1i,
                                                float* __restrict__ s1cc,
                                                float* __restrict__ s1d,
                                                int M, int nPrim, int slabBase) {
    if (blockIdx.x >= nPrim) {
        int wave = threadIdx.x >> 6;
        int slab = slabBase + (blockIdx.x - nPrim) * 4 + wave;
        dev_gemm1(slab, A, Bt, h1i, s1cc, s1d, M);
        return;
    }
    __shared__ int h[1024];
    int t = threadIdx.x;
    for (int i = t; i < nbuck; i += 256) h[i] = 0;
    __syncthreads();
    int base = blockIdx.x * EPB;
    #pragma unroll
    for (int r = 0; r < 4; ++r) {
        int i4 = base + (r * 256 + t) * 4;
        if (i4 + 3 < E) {
            int4 d = *(const int4*)(ei + E + i4);
            atomicAdd(&h[d.x >> 7], 1);
            atomicAdd(&h[d.y >> 7], 1);
            atomicAdd(&h[d.z >> 7], 1);
            atomicAdd(&h[d.w >> 7], 1);
        } else {
            for (int j = i4; j < E; ++j) atomicAdd(&h[ei[E + j] >> 7], 1);
        }
    }
    __syncthreads();
    int* crow = counts + (size_t)blockIdx.x * nbuck;
    for (int i = t; i < nbuck; i += 256) crow[i] = h[i];
}

// ---------------- P2: per-bucket exclusive scan across blocks --------------
__global__ __launch_bounds__(256) void k_scan_cols(int* __restrict__ counts,
                                                   int* __restrict__ totals,
                                                   int nb1, int nbuck) {
    __shared__ int wsum[4];
    int k = blockIdx.x;
    int t = threadIdx.x, lane = t & 63, wv = t >> 6;
    int e0 = 2 * t, e1 = 2 * t + 1;
    int v0 = (e0 < nb1) ? counts[(size_t)e0 * nbuck + k] : 0;
    int v1 = (e1 < nb1) ? counts[(size_t)e1 * nbuck + k] : 0;
    int s = v0 + v1;
    int incl = s;
    #pragma unroll
    for (int off = 1; off < 64; off <<= 1) {
        int u = __shfl_up(incl, off, 64);
        if (lane >= off) incl += u;
    }
    if (lane == 63) wsum[wv] = incl;
    __syncthreads();
    int add = 0;
    if (wv > 0) add += wsum[0];
    if (wv > 1) add += wsum[1];
    if (wv > 2) add += wsum[2];
    incl += add;
    int excl = incl - s;
    if (e0 < nb1) counts[(size_t)e0 * nbuck + k] = excl;
    if (e1 < nb1) counts[(size_t)e1 * nbuck + k] = excl + v0;
    if (t == 255) totals[k] = incl;
}

// ---------------- P3: bucket-contiguous placement (+ gemm chunk) -----------
__global__ __launch_bounds__(256) void k_place_g1(const int* __restrict__ ei, int E,
                                                  const int* __restrict__ counts,
                                                  const int* __restrict__ totals,
                                                  int* __restrict__ bstart,
                                                  uintT* __restrict__ tmp, int nbuck,
                                                  const float* __restrict__ A,
                                                  const ushortT* __restrict__ Bt,
                                                  ucharT* __restrict__ h1i,
                                                  float* __restrict__ s1cc,
                                                  float* __restrict__ s1d,
                                                  int M, int nPrim, int slabBase) {
    if (blockIdx.x >= nPrim) {
        int wave = threadIdx.x >> 6;
        int slab = slabBase + (blockIdx.x - nPrim) * 4 + wave;
        dev_gemm1(slab, A, Bt, h1i, s1cc, s1d, M);
        return;
    }
    __shared__ int st[1024];
    __shared__ int pos[1024];
    __shared__ int wsum[4];
    int t = threadIdx.x, lane = t & 63, wv = t >> 6;
    int b = blockIdx.x;
    int g[4];
    int s = 0;
    #pragma unroll
    for (int j = 0; j < 4; ++j) {
        int e = 4 * t + j;
        g[j] = (e < nbuck) ? totals[e] : 0;
        s += g[j];
    }
    int incl = s;
    #pragma unroll
    for (int off = 1; off < 64; off <<= 1) {
        int u = __shfl_up(incl, off, 64);
        if (lane >= off) incl += u;
    }
    if (lane == 63) wsum[wv] = incl;
    __syncthreads();
    int add = 0;
    if (wv > 0) add += wsum[0];
    if (wv > 1) add += wsum[1];
    if (wv > 2) add += wsum[2];
    int excl = incl + add - s;
    #pragma unroll
    for (int j = 0; j < 4; ++j) {
        int e = 4 * t + j;
        if (e < nbuck) st[e] = excl;
        excl += g[j];
    }
    __syncthreads();
    const int* crow = counts + (size_t)b * nbuck;
    for (int i = t; i < nbuck; i += 256) {
        int sv = st[i];
        pos[i] = sv + crow[i];
        if (b == 0) bstart[i] = sv;
    }
    __syncthreads();
    int base = b * EPB;
    #pragma unroll
    for (int r = 0; r < 4; ++r) {
        int i4 = base + (r * 256 + t) * 4;
        if (i4 + 3 < E) {
            int4 sv = *(const int4*)(ei + i4);
            int4 dv = *(const int4*)(ei + E + i4);
            int p0 = atomicAdd(&pos[dv.x >> 7], 1);
            tmp[p0] = (uintT)sv.x | (((uintT)dv.x & 127u) << 17);
            int p1 = atomicAdd(&pos[dv.y >> 7], 1);
            tmp[p1] = (uintT)sv.y | (((uintT)dv.y & 127u) << 17);
            int p2 = atomicAdd(&pos[dv.z >> 7], 1);
            tmp[p2] = (uintT)sv.z | (((uintT)dv.z & 127u) << 17);
            int p3 = atomicAdd(&pos[dv.w >> 7], 1);
            tmp[p3] = (uintT)sv.w | (((uintT)dv.w & 127u) << 17);
        } else {
            for (int j = i4; j < E; ++j) {
                int sj = ei[j], dj = ei[E + j];
                int p = atomicAdd(&pos[dj >> 7], 1);
                tmp[p] = (uintT)sj | (((uintT)dj & 127u) << 17);
            }
        }
    }
}

// ---------------- P4 worker: per-bucket CSR finalize ------------------------
static __device__ __forceinline__ void dev_csr(int k,
                                               const uintT* __restrict__ tmp,
                                               const int* __restrict__ bstart,
                                               const int* __restrict__ totals,
                                               int* __restrict__ rowptr,
                                               int* __restrict__ csr_src,
                                               int N, int* cnt, int* cur,
                                               int* wtot) {
    int t = threadIdx.x;
    int nodeBase = k << 7;
    int nn = N - nodeBase;
    if (nn > 128) nn = 128;
    int myStart = bstart[k];
    int myCount = totals[k];
    int csrBase = myStart + nodeBase;   // + self loops of preceding nodes
    if (t < 128) cnt[t] = 0;
    __syncthreads();
    for (int i = t; i < myCount; i += 256) {
        uintT p = tmp[myStart + i];
        atomicAdd(&cnt[p >> 17], 1);
    }
    __syncthreads();
    int dseg = 0, incl = 0;
    if (t < 128) {
        dseg = (t < nn) ? cnt[t] + 1 : 0;   // +1 self loop
        incl = dseg;
        #pragma unroll
        for (int off = 1; off < 64; off <<= 1) {
            int u = __shfl_up(incl, off, 64);
            if ((t & 63) >= off) incl += u;
        }
        if (t == 63) *wtot = incl;
    }
    __syncthreads();
    if (t < nn) {
        int excl = incl - dseg + ((t >= 64) ? *wtot : 0);
        int rp = csrBase + excl;
        int node = nodeBase + t;
        rowptr[node + 1] = rp + dseg;
        csr_src[rp] = node;              // self loop first
        cur[t] = rp + 1;
    }
    if (k == 0 && t == 0) rowptr[0] = 0;
    __syncthreads();
    for (int i = t; i < myCount; i += 256) {
        uintT p = tmp[myStart + i];
        int ld = p >> 17;
        int q = atomicAdd(&cur[ld], 1);
        csr_src[q] = (int)(p & 0x1FFFFu);
    }
}

// ---------------- P4a: buckets [0, nPrim) (+ gemm chunk) -------------------
__global__ __launch_bounds__(256) void k_csr_g1(const uintT* __restrict__ tmp,
                                                const int* __restrict__ bstart,
                                                const int* __restrict__ totals,
                                                int* __restrict__ rowptr,
                                                int* __restrict__ csr_src,
                                                int N,
                                                const float* __restrict__ A,
                                                const ushortT* __restrict__ Bt,
                                                ucharT* __restrict__ h1i,
                                                float* __restrict__ s1cc,
                                                float* __restrict__ s1d,
                                                int M, int nPrim, int slabBase) {
    __shared__ int cnt[128];
    __shared__ int cur[128];
    __shared__ int wtot;
    if (blockIdx.x >= nPrim) {
        int wave = threadIdx.x >> 6;
        int slab = slabBase + (blockIdx.x - nPrim) * 4 + wave;
        dev_gemm1(slab, A, Bt, h1i, s1cc, s1d, M);
        return;
    }
    dev_csr(blockIdx.x, tmp, bstart, totals, rowptr, csr_src, N, cnt, cur, &wtot);
}

// ---------------- layer-1 aggregation worker (2 nodes/wave) -----------------
// Per 32-lane half: one node, 2 edge slots x 16 ch-lanes; rotation-free 3x
// pipeline, index prefetched 1 rotation ahead. Reduce = single xor-16.
struct Edge1 {
    float2 svc;       // (score_head, row scale)
    uint4 v;
    int si;
};

static __device__ __forceinline__ void ldi1(Edge1& S, int j, int endm1,
                                            const int* __restrict__ csr_src) {
    int jj = j < endm1 ? j : endm1;
    S.si = csr_src[jj];
}

static __device__ __forceinline__ void ldv1(Edge1& S, int j, int end,
                                            const float2* __restrict__ sc2,
                                            const ucharT* __restrict__ hb, int head) {
    if (j < end) {
        int s = S.si;
        S.svc = sc2[((size_t)s << 3) + head];
        S.v = *(const uint4*)(hb + ((size_t)s << 8));
    }
}

static __device__ __forceinline__ void ac1(const Edge1& S, float sdn,
                                           float2v* A, float& l, float& sps) {
    float p = exp2f(lrelu(S.svc.x + sdn));   // scores pre-scaled by log2e
    l += p;
    float ps = p * S.svc.y;
    sps += ps;
    float2v p2 = {ps, ps};
    uintT w;
    w = S.v.x;
    A[0] += p2 * (float2v){ub(w, 0), ub(w, 1)};
    A[1] += p2 * (float2v){ub(w, 2), ub(w, 3)};
    w = S.v.y;
    A[2] += p2 * (float2v){ub(w, 0), ub(w, 1)};
    A[3] += p2 * (float2v){ub(w, 2), ub(w, 3)};
    w = S.v.z;
    A[4] += p2 * (float2v){ub(w, 0), ub(w, 1)};
    A[5] += p2 * (float2v){ub(w, 2), ub(w, 3)};
    w = S.v.w;
    A[6] += p2 * (float2v){ub(w, 0), ub(w, 1)};
    A[7] += p2 * (float2v){ub(w, 2), ub(w, 3)};
}

static __device__ __forceinline__ void dev_agg1_pair(int n0, int NN,
                                                     const ucharT* __restrict__ h1i,
                                                     const float* __restrict__ s1cc,
                                                     const float* __restrict__ s1d,
                                                     const int* __restrict__ rowptr,
                                                     const int* __restrict__ csr_src,
                                                     const float* __restrict__ b1,
                                                     ushortT* __restrict__ out1) {
    int lane = threadIdx.x & 63;
    int half = lane >> 5;
    int n = n0 + half;
    bool act = n < NN;
    int l32 = lane & 31;
    int g = l32 >> 4;            // 2 edge slots per half
    int cl = l32 & 15;           // 16 channels each
    int head = cl >> 1;
    int beg = 0, end = 0;
    if (act) {
        beg = rowptr[n];
        end = rowptr[n + 1];
    }
    float sdn = act ? s1d[(size_t)n * 8 + head] : 0.f;
    const ucharT* hb = h1i + cl * 16;
    const float2* sc2 = (const float2*)s1cc;
    float2v A[8];
    #pragma unroll
    for (int k = 0; k < 8; ++k) A[k] = (float2v){0.f, 0.f};
    float l = 0.f, sps = 0.f;
    int i0 = beg + g;
    if (i0 < end) {
        int endm1 = end - 1;
        Edge1 S0, S1, S2;
        S0.svc = S1.svc = S2.svc = make_float2(0.f, 0.f);
        S0.v = S1.v = S2.v = make_uint4(0u, 0u, 0u, 0u);
        ldi1(S0, i0, endm1, csr_src);
        ldi1(S1, i0 + 2, endm1, csr_src);
        ldi1(S2, i0 + 4, endm1, csr_src);
        ldv1(S0, i0, end, sc2, hb, head);
        ldv1(S1, i0 + 2, end, sc2, hb, head);
        ldv1(S2, i0 + 4, end, sc2, hb, head);
        ldi1(S0, i0 + 6, endm1, csr_src);
        ldi1(S1, i0 + 8, endm1, csr_src);
        ldi1(S2, i0 + 10, endm1, csr_src);
        for (int idx = i0; idx < end; idx += 6) {
            ac1(S0, sdn, A, l, sps);
            ldv1(S0, idx + 6, end, sc2, hb, head);
            ldi1(S0, idx + 12, endm1, csr_src);
            if (idx + 2 < end) {
                ac1(S1, sdn, A, l, sps);
                ldv1(S1, idx + 8, end, sc2, hb, head);
                ldi1(S1, idx + 14, endm1, csr_src);
            }
            if (idx + 4 < end) {
                ac1(S2, sdn, A, l, sps);
                ldv1(S2, idx + 10, end, sc2, hb, head);
                ldi1(S2, idx + 16, endm1, csr_src);
            }
        }
    }
    // reduce across the 2 slots (xor-16 stays inside the 32-lane half)
    l += __shfl_xor(l, 16, 64);
    sps += __shfl_xor(sps, 16, 64);
    #pragma unroll
    for (int k = 0; k < 8; ++k) {
        A[k].x += __shfl_xor(A[k].x, 16, 64);
        A[k].y += __shfl_xor(A[k].y, 16, 64);
    }
    if (g == 0 && act) {
        float inv = 1.f / l;
        float adj = 128.f * sps;            // undo the uint8 bias
        const float4 bb0 = *(const float4*)(b1 + cl * 16);
        const float4 bb1 = *(const float4*)(b1 + cl * 16 + 4);
        const float4 bb2 = *(const float4*)(b1 + cl * 16 + 8);
        const float4 bb3 = *(const float4*)(b1 + cl * 16 + 12);
        float bbf[16] = {bb0.x, bb0.y, bb0.z, bb0.w, bb1.x, bb1.y, bb1.z, bb1.w,
                         bb2.x, bb2.y, bb2.z, bb2.w, bb3.x, bb3.y, bb3.z, bb3.w};
        uintT o[8];
        #pragma unroll
        for (int k = 0; k < 8; ++k) {
            float x0 = fmaxf((A[k].x - adj) * inv + bbf[2 * k], 0.f);
            float x1 = fmaxf((A[k].y - adj) * inv + bbf[2 * k + 1], 0.f);
            o[k] = pk(x0, x1);
        }
        *(uint4*)(out1 + (size_t)n * 256 + cl * 16) =
            make_uint4(o[0], o[1], o[2], o[3]);
        *(uint4*)(out1 + (size_t)n * 256 + cl * 16 + 8) =
            make_uint4(o[4], o[5], o[6], o[7]);
    }
}

// ---------------- fused: P4b (buckets >= halfB) ∥ agg1 nodes [0, H) --------
__global__ __launch_bounds__(256) void k_csr_agg1(const uintT* __restrict__ tmp,
                                                  const int* __restrict__ bstart,
                                                  const int* __restrict__ totals,
                                                  int* __restrict__ rowptr,
                                                  int* __restrict__ csr_src,
                                                  int N, int halfB, int nP4,
                                                  const ucharT* __restrict__ h1i,
                                                  const float* __restrict__ s1cc,
                                                  const float* __restrict__ s1d,
                                                  const float* __restrict__ b1,
                                                  ushortT* __restrict__ out1, int H) {
    __shared__ int cnt[128];
    __shared__ int cur[128];
    __shared__ int wtot;
    if (blockIdx.x < nP4) {
        dev_csr(halfB + blockIdx.x, tmp, bstart, totals, rowptr, csr_src, N,
                cnt, cur, &wtot);
        return;
    }
    int n0 = (blockIdx.x - nP4) * 8 + (threadIdx.x >> 6) * 2;
    if (n0 >= H) return;
    dev_agg1_pair(n0, H, h1i, s1cc, s1d, rowptr, csr_src, b1, out1);
}

// ---------------- agg1 tail: nodes [H, N) ----------------------------------
__global__ __launch_bounds__(256) void k_agg1(const ucharT* __restrict__ h1i,
                                              const float* __restrict__ s1cc,
                                              const float* __restrict__ s1d,
                                              const int* __restrict__ rowptr,
                                              const int* __restrict__ csr_src,
                                              const float* __restrict__ b1,
                                              ushortT* __restrict__ out1,
                                              int base, int N) {
    int n0 = base + blockIdx.x * 8 + (threadIdx.x >> 6) * 2;
    if (n0 >= N) return;
    dev_agg1_pair(n0, N, h1i, s1cc, s1d, rowptr, csr_src, b1, out1);
}

// ---------------- GEMM2: out1b[M,256] @ W2 -> h2 rows (stride 48) + s2d ----
// H2 row: cols 0..39 bf16, src-score f32 (pre-scaled) embedded at +40.
__global__ __launch_bounds__(256) void k_gemm2(const ushortT* __restrict__ X,
                                               const ushortT* __restrict__ Bt,
                                               const float* __restrict__ a2s,
                                               const float* __restrict__ a2d,
                                               ushortT* __restrict__ H2,
                                               float* __restrict__ s2d, int M) {
    int lane = threadIdx.x & 63, wave = threadIdx.x >> 6;
    int slab = blockIdx.x * 4 + wave;
    int r0 = slab * 16;
    if (r0 >= M) return;
    int n = lane & 15, q = lane >> 4;
    const ushortT* xrow = X + (size_t)(r0 + n) * 256 + q * 8;
    float4v acc[3];
    #pragma unroll
    for (int j = 0; j < 3; ++j) acc[j] = (float4v){0.f, 0.f, 0.f, 0.f};
    #pragma unroll
    for (int s = 0; s < 8; ++s) {
        short8 a = *(const short8*)(xrow + s * 32);
        #pragma unroll
        for (int j = 0; j < 3; ++j) {
            short8 b = *(const short8*)(Bt + (size_t)(j * 16 + n) * 256 + s * 32 + q * 8);
            acc[j] = __builtin_amdgcn_mfma_f32_16x16x32_bf16(a, b, acc[j], 0, 0, 0);
        }
    }
    float asv[3], adv[3];
    #pragma unroll
    for (int j = 0; j < 3; ++j) {
        int col = j * 16 + n;
        asv[j] = (col < 40) ? a2s[col] * LOG2E : 0.f;
        adv[j] = (col < 40) ? a2d[col] * LOG2E : 0.f;
    }
    float us[4], ud[4];
    #pragma unroll
    for (int r = 0; r < 4; ++r) {
        us[r] = acc[0][r] * asv[0] + acc[1][r] * asv[1] + acc[2][r] * asv[2];
        ud[r] = acc[0][r] * adv[0] + acc[1][r] * adv[1] + acc[2][r] * adv[2];
    }
    #pragma unroll
    for (int off = 1; off < 16; off <<= 1) {
        #pragma unroll
        for (int r = 0; r < 4; ++r) {
            us[r] += __shfl_xor(us[r], off, 64);
            ud[r] += __shfl_xor(ud[r], off, 64);
        }
    }
    #pragma unroll
    for (int j = 0; j < 3; ++j) {
        int col = j * 16 + n;
        if (col < 40) {
            #pragma unroll
            for (int r = 0; r < 4; ++r)
                H2[(size_t)(r0 + q * 4 + r) * 48 + col] = f2bf(acc[j][r]);
        }
    }
    if (n == 0) {
        #pragma unroll
        for (int r = 0; r < 4; ++r) {
            int row = r0 + q * 4 + r;
            *(float*)(H2 + (size_t)row * 48 + 40) = us[r];
            s2d[row] = ud[r];
        }
    }
}

// ---------------- layer-2 aggregation + log_softmax ------------------------
// 6 edge slots x 10 ch-lanes; two-level 3x pipeline; staged slot-fold reduce.
struct Edge2 {
    float sv;
    uint2 v;
    int si;
};

static __device__ __forceinline__ void ldi2(Edge2& S, int j, int endm1,
                                            const int* __restrict__ csr_src) {
    int jj = j < endm1 ? j : endm1;
    S.si = csr_src[jj];
}

static __device__ __forceinline__ void ldv2(Edge2& S, int j, int end,
                                            const ushortT* __restrict__ h2, int cl) {
    if (j < end) {
        int s = S.si;
        const ushortT* hr = h2 + (size_t)s * 48;
        S.v = *(const uint2*)(hr + cl * 4);
        S.sv = *(const float*)(hr + 40);
    }
}

static __device__ __forceinline__ void ac2(const Edge2& S, float sdn,
                                           float2v& A01, float2v& A23, float& l) {
    float p = exp2f(lrelu(S.sv + sdn));   // pre-scaled scores
    l += p;
    float2v p2 = {p, p};
    A01 += p2 * (float2v){bflo(S.v.x), bfhi(S.v.x)};
    A23 += p2 * (float2v){bflo(S.v.y), bfhi(S.v.y)};
}

__global__ __launch_bounds__(256) void k_agg2lsm(const ushortT* __restrict__ h2,
                                                 const float* __restrict__ sd,
                                                 const int* __restrict__ rowptr,
                                                 const int* __restrict__ csr_src,
                                                 const float* __restrict__ b2,
                                                 float* __restrict__ out, int N) {
    int lane = threadIdx.x & 63;
    int wid = threadIdx.x >> 6;
    int n = blockIdx.x * 4 + wid;
    if (n >= N) return;
    int el = lane / 10;
    int cl = lane - el * 10;
    int beg = rowptr[n], end = rowptr[n + 1];
    float sdn = sd[n];
    float2v A01 = (float2v){0.f, 0.f}, A23 = (float2v){0.f, 0.f};
    float l = 0.f;
    if (el < 6) {
        int i0 = beg + el;
        if (i0 < end) {
            int endm1 = end - 1;
            Edge2 S0, S1, S2;
            S0.sv = S1.sv = S2.sv = 0.f;
            S0.v = S1.v = S2.v = make_uint2(0u, 0u);
            ldi2(S0, i0, endm1, csr_src);
            ldi2(S1, i0 + 6, endm1, csr_src);
            ldi2(S2, i0 + 12, endm1, csr_src);
            ldv2(S0, i0, end, h2, cl);
            ldv2(S1, i0 + 6, end, h2, cl);
            ldv2(S2, i0 + 12, end, h2, cl);
            ldi2(S0, i0 + 18, endm1, csr_src);
            ldi2(S1, i0 + 24, endm1, csr_src);
            ldi2(S2, i0 + 30, endm1, csr_src);
            for (int idx = i0; idx < end; idx += 18) {
                ac2(S0, sdn, A01, A23, l);
                ldv2(S0, idx + 18, end, h2, cl);
                ldi2(S0, idx + 36, endm1, csr_src);
                if (idx + 6 < end) {
                    ac2(S1, sdn, A01, A23, l);
                    ldv2(S1, idx + 24, end, h2, cl);
                    ldi2(S1, idx + 42, endm1, csr_src);
                }
                if (idx + 12 < end) {
                    ac2(S2, sdn, A01, A23, l);
                    ldv2(S2, idx + 30, end, h2, cl);
                    ldi2(S2, idx + 48, endm1, csr_src);
                }
            }
        }
    }
    float a0 = A01.x, a1 = A01.y, a2 = A23.x, a3 = A23.y;
    // staged slot fold: (3..5)->(0..2), then (0..2)->el==0 lanes 0..9
    int src = lane + 30;
    if (src > 63) src = 63;
    bool f = (el < 3);
    float u;
    u = __shfl(a0, src, 64); if (f) a0 += u;
    u = __shfl(a1, src, 64); if (f) a1 += u;
    u = __shfl(a2, src, 64); if (f) a2 += u;
    u = __shfl(a3, src, 64); if (f) a3 += u;
    u = __shfl(l, src, 64);  if (f) l += u;
    int s1 = cl + 10, s2 = cl + 20;
    float t0 = a0 + __shfl(a0, s1, 64) + __shfl(a0, s2, 64);
    float t1 = a1 + __shfl(a1, s1, 64) + __shfl(a1, s2, 64);
    float t2 = a2 + __shfl(a2, s1, 64) + __shfl(a2, s2, 64);
    float t3 = a3 + __shfl(a3, s1, 64) + __shfl(a3, s2, 64);
    float lt = l + __shfl(l, s1, 64) + __shfl(l, s2, 64);
    float inv = 1.f / lt;
    float o0 = t0 * inv + b2[cl * 4 + 0];
    float o1 = t1 * inv + b2[cl * 4 + 1];
    float o2 = t2 * inv + b2[cl * 4 + 2];
    float o3 = t3 * inv + b2[cl * 4 + 3];
    float lm = (lane < 10) ? fmaxf(fmaxf(o0, o1), fmaxf(o2, o3)) : -INFINITY;
    #pragma unroll
    for (int off = 32; off; off >>= 1) lm = fmaxf(lm, __shfl_xor(lm, off, 64));
    float le = (lane < 10)
        ? __expf(o0 - lm) + __expf(o1 - lm) + __expf(o2 - lm) + __expf(o3 - lm)
        : 0.f;
    #pragma unroll
    for (int off = 32; off; off >>= 1) le += __shfl_xor(le, off, 64);
    float ls = lm + logf(le);
    if (lane < 10) {
        float4 w = make_float4(o0 - ls, o1 - ls, o2 - ls, o3 - ls);
        *(float4*)(out + (size_t)n * 40 + cl * 4) = w;
    }
}

// ---------------------------------------------------------------------------
extern "C" void kernel_launch(void* const* d_in, const int* in_sizes, int n_in,
                              void* d_out, int out_size, void* d_ws, size_t ws_size,
                              hipStream_t stream) {
    const float* x   = (const float*)d_in[0];
    const int*   ei  = (const int*)d_in[1];
    const float* W1  = (const float*)d_in[2];
    const float* a1s = (const float*)d_in[3];
    const float* a1d = (const float*)d_in[4];
    const float* b1  = (const float*)d_in[5];
    const float* W2  = (const float*)d_in[6];
    const float* a2s = (const float*)d_in[7];
    const float* a2d = (const float*)d_in[8];
    const float* b2  = (const float*)d_in[9];
    float* out = (float*)d_out;

    const int N = in_sizes[0] / 128;   // 100000
    const int E = in_sizes[1] / 2;     // 1600000
    const int ET = E + N;
    const int NBUCK = (N + 127) >> 7;              // 782
    const int NB1 = (E + EPB - 1) / EPB;           // 391

    // ---- workspace layout ----
    char* w = (char*)d_ws;
    ucharT* h1i = (ucharT*)w;                             // N*256 u8 (25.6 MB)
    ushortT* out1b = (ushortT*)(w + (size_t)N * 256);     // N*256 bf16 (51.2 MB)
    int* i_row = (int*)(w + (size_t)N * 768);             // N+16 ints
    float* s1cc = (float*)(w + (size_t)N * 768 + ((size_t)N + 16) * 4); // N*16 f32
    float* s1d = s1cc + (size_t)N * 16;                   // N*8 f32
    int* i_cnt = (int*)(s1d + (size_t)N * 8);             // NB1*NBUCK
    int* i_tot = i_cnt + (size_t)NB1 * NBUCK;             // NBUCK+2
    int* i_bst = i_tot + NBUCK + 2;                       // NBUCK+2
    uintT* i_tmp = (uintT*)(i_bst + NBUCK + 2);           // E packed pairs
    int* i_csr = (int*)(i_tmp + E);                       // ET ints
    ushortT* W1t = (ushortT*)(i_csr + ET);                // 272*128 bf16
    ushortT* W2t = W1t + 272 * 128;                       // 48*256 bf16
    // layer-2 overlays (dead after agg1 / P3):
    //   h2b (N*48 ushort = N*96 B) over s1cc+s1d (N*64 + N*32 = N*96 B, exact)
    //   s2d (N f32) over i_cnt (dead after P3; P4 uses bstart/totals only)
    ushortT* h2b = (ushortT*)s1cc;
    float* s2d = (float*)i_cnt;

    const int nb4 = (N + 3) / 4;
    const int nbG = (N / 16 + 3) / 4;            // gemm blocks (4 waves x 16 rows)
    const int CH  = (nbG + 2) / 3;               // gemm1 chunk (blocks)
    const int halfB = NBUCK >> 1;                // 391
    const int H = halfB << 7;                    // 50048 nodes in first half
    const int nP4b = NBUCK - halfB;              // 391
    const int nAgg1a = (H + 7) / 8;              // agg1 pair blocks, first half
    const int nAgg1b = (N - H + 7) / 8;          // agg1 pair blocks, tail

    // ---- L0: weight prep ----
    k_prep<<<PREP_BLOCKS, 256, 0, stream>>>(W1, W2, a1s, a1d, W1t, W2t);
    // ---- P1: bucket histogram ∥ gemm1 chunk 0 ----
    k_cnt_g1<<<NB1 + CH, 256, 0, stream>>>(ei, E, i_cnt, NBUCK,
                                           x, W1t, h1i, s1cc, s1d,
                                           N, NB1, 0);
    // ---- P2: per-bucket scan across blocks ----
    k_scan_cols<<<NBUCK, 256, 0, stream>>>(i_cnt, i_tot, NB1, NBUCK);
    // ---- P3: bucket-contiguous placement ∥ gemm1 chunk 1 ----
    k_place_g1<<<NB1 + CH, 256, 0, stream>>>(ei, E, i_cnt, i_tot, i_bst, i_tmp, NBUCK,
                                             x, W1t, h1i, s1cc, s1d,
                                             N, NB1, CH * 4);
    // ---- P4a: CSR finalize buckets [0, halfB) ∥ gemm1 chunk 2 ----
    k_csr_g1<<<halfB + CH, 256, 0, stream>>>(i_tmp, i_bst, i_tot, i_row, i_csr, N,
                                             x, W1t, h1i, s1cc, s1d,
                                             N, halfB, CH * 8);
    // ---- P4b ∥ agg1 nodes [0, H) ----
    k_csr_agg1<<<nP4b + nAgg1a, 256, 0, stream>>>(i_tmp, i_bst, i_tot, i_row, i_csr,
                                                  N, halfB, nP4b,
                                                  h1i, s1cc, s1d, b1, out1b, H);
    // ---- agg1 tail: nodes [H, N) ----
    k_agg1<<<nAgg1b, 256, 0, stream>>>(h1i, s1cc, s1d, i_row, i_csr, b1,
                                       out1b, H, N);

    // ---- layer 2 ----
    k_gemm2<<<nbG, 256, 0, stream>>>(out1b, W2t, a2s, a2d, h2b, s2d, N);
    k_agg2lsm<<<nb4, 256, 0, stream>>>(h2b, s2d, i_row, i_csr, b2, out, N);
}

// Round 10
// 396.614 us; speedup vs baseline: 1.0266x; 1.0055x over previous
//
#include <hip/hip_runtime.h>
#include <hip/hip_bf16.h>
#include <cmath>

// ---------------------------------------------------------------------------
// GAT 2-layer forward.  (R9 resubmission with overlay-alignment hardening:
// i_tmp is now aligned UP to 64B at layout time so the h2i overlay cannot
// intrude into live i_bst entries regardless of d_ws base alignment.)
//  - LDS-free MFMA GEMMs (A direct global->reg, B pre-transposed bf16).
//  - scores1 fused into GEMM1 (extra 16 cols via Wa = W1 @ blockdiag(a)),
//    Wa PRE-SCALED by log2e -> agg kernels use exp2f (bare v_exp_f32).
//  - h1 stored BIASED UINT8 (q+128) with per-row scale; agg1 unpacks with
//    v_cvt_f32_ubyte{0..3}, corrected by 128*sum(p*scale) in the epilogue.
//  - s1cc[node][head] = float2(score_h, scale): 64B-aligned records.
//  - agg1: TWO NODES PER WAVE (32-lane halves), 2 slots x 16 ch-lanes each.
//  - h2 ALSO biased int8: 64-byte rows = 40 int8 + float2(score,scale) at +40;
//    ONE cache line per edge in agg2 (was 2). Table (6.4 MB) overlays dead
//    i_tmp -> gemm2 rows [0,H) co-launch with agg1 tail (no s1cc conflict).
//  - W2t has 64 storage cols, permuted storage(j,n) -> col 4n+j so each lane
//    packs its 4 cols into one dword int8 store.
//  - agg2: TWO NODES PER WAVE (3 slots x 10 ch-lanes per half), staged fold.
//  - Two-level rotation-free 3x pipelines (index 1 rotation ahead).
//  - CSR build WITHOUT global atomics (bucketed counting sort P1..P4);
//    gemm1 in 3 chunks under P1/P3/P4a; P4b co-launched with agg1 half 1.
//  - log_softmax fused into agg2.
// ---------------------------------------------------------------------------

typedef unsigned short ushortT;
typedef unsigned int uintT;
typedef unsigned char ucharT;
typedef __attribute__((ext_vector_type(8))) short short8;
typedef __attribute__((ext_vector_type(4))) float float4v;
typedef __attribute__((ext_vector_type(2))) float float2v;

#define LOG2E 1.4426950408889634f

static __device__ __forceinline__ ushortT f2bf(float f) {
    __hip_bfloat16 h = __float2bfloat16(f);   // RNE
    return *reinterpret_cast<ushortT*>(&h);
}
static __device__ __forceinline__ uintT pk(float a, float b) {
    return (uintT)f2bf(a) | ((uintT)f2bf(b) << 16);
}
static __device__ __forceinline__ float ub(uintT u, int k) {   // unsigned byte k
    return (float)((u >> (8 * k)) & 0xffu);                    // -> v_cvt_f32_ubyteN
}
// leaky: e>=0 -> e ; e<0 -> 0.2e.  0.6e + 0.4|e| (2 VALU, abs = modifier)
static __device__ __forceinline__ float lrelu(float e) {
    return 0.6f * e + 0.4f * fabsf(e);
}

#define PREP_BLOCKS 200
#define EPB 4096              // edges per histogram/placement block

// ---------------- prep: transpose weights to bf16 + score matrix -----------
// W2t: 64 x 256, storage row s=(j<<4)|n holds ORIGINAL col 4n+j (n<10).
__global__ __launch_bounds__(256) void k_prep(const float* __restrict__ W1,
                                              const float* __restrict__ W2,
                                              const float* __restrict__ a1s,
                                              const float* __restrict__ a1d,
                                              ushortT* __restrict__ W1t,
                                              ushortT* __restrict__ W2t) {
    int t = blockIdx.x * 256 + threadIdx.x;
    if (t < 128 * 256) {
        int k = t >> 8, s = t & 255;
        int c = ((s & 15) << 4) | (s >> 4);
        W1t[s * 128 + k] = f2bf(W1[(size_t)k * 256 + c]);
    } else if (t < 128 * 256 + 64 * 256) {
        int q = t - 128 * 256;
        int k = q >> 6, s = q & 63;
        int n = s & 15, j = s >> 4;
        int c = 4 * n + j;
        W2t[s * 256 + k] = (n < 10) ? f2bf(W2[k * 40 + c]) : (ushortT)0;
    } else if (t < 128 * 256 + 64 * 256 + 2048) {
        int q = t - (128 * 256 + 64 * 256);
        int k = q >> 4, j = q & 15;
        int h = j & 7;
        const float* av = ((j < 8) ? a1s : a1d) + h * 32;
        const float* wr = W1 + (size_t)k * 256 + h * 32;
        float s = 0.f;
        #pragma unroll
        for (int c = 0; c < 32; ++c) s += wr[c] * av[c];
        W1t[(256 + j) * 128 + k] = f2bf(s * LOG2E);   // pre-scaled for exp2
    }
}

// ---------------- GEMM1 worker: x[16,128] @ W1 -> biased-u8 h1i + s1cc/s1d -
static __device__ __forceinline__ void dev_gemm1(int slab,
                                                 const float* __restrict__ A,
                                                 const ushortT* __restrict__ Bt,
                                                 ucharT* __restrict__ h1i,
                                                 float* __restrict__ s1cc,
                                                 float* __restrict__ s1d, int M) {
    int lane = threadIdx.x & 63;
    int r0 = slab * 16;
    if (r0 >= M) return;
    int n = lane & 15, q = lane >> 4;
    const float* arow = A + (size_t)(r0 + n) * 128 + q * 8;
    short8 af[4];
    #pragma unroll
    for (int s = 0; s < 4; ++s) {
        float4 v0 = *(const float4*)(arow + s * 32);
        float4 v1 = *(const float4*)(arow + s * 32 + 4);
        short8 a;
        a[0] = (short)f2bf(v0.x); a[1] = (short)f2bf(v0.y);
        a[2] = (short)f2bf(v0.z); a[3] = (short)f2bf(v0.w);
        a[4] = (short)f2bf(v1.x); a[5] = (short)f2bf(v1.y);
        a[6] = (short)f2bf(v1.z); a[7] = (short)f2bf(v1.w);
        af[s] = a;
    }
    float4v acc[17];
    #pragma unroll
    for (int j = 0; j < 17; ++j) acc[j] = (float4v){0.f, 0.f, 0.f, 0.f};
    #pragma unroll
    for (int s = 0; s < 4; ++s) {
        #pragma unroll
        for (int j = 0; j < 17; ++j) {
            short8 b = *(const short8*)(Bt + (size_t)(j * 16 + n) * 128 + s * 32 + q * 8);
            acc[j] = __builtin_amdgcn_mfma_f32_16x16x32_bf16(af[s], b, acc[j], 0, 0, 0);
        }
    }
    float am[4];
    #pragma unroll
    for (int r = 0; r < 4; ++r) {
        float m = 0.f;
        #pragma unroll
        for (int j = 0; j < 16; ++j) m = fmaxf(m, fabsf(acc[j][r]));
        am[r] = m;
    }
    #pragma unroll
    for (int off = 1; off < 16; off <<= 1) {
        #pragma unroll
        for (int r = 0; r < 4; ++r) am[r] = fmaxf(am[r], __shfl_xor(am[r], off, 64));
    }
    #pragma unroll
    for (int r = 0; r < 4; ++r) {
        int row = r0 + q * 4 + r;
        float m = am[r];
        float si = (m > 0.f) ? 127.f / m : 0.f;
        uintT wd[4];
        #pragma unroll
        for (int wq = 0; wq < 4; ++wq) {
            uintT p4 = 0;
            #pragma unroll
            for (int b = 0; b < 4; ++b) {
                int j = wq * 4 + b;
                int qv = (int)rintf(acc[j][r] * si) + 128;   // biased uint8
                p4 |= ((uintT)(qv & 0xff)) << (8 * b);
            }
            wd[wq] = p4;
        }
        uint4 o = make_uint4(wd[0], wd[1], wd[2], wd[3]);
        *(uint4*)(h1i + (size_t)row * 256 + n * 16) = o;
        float vv = acc[16][r];
        if (n < 8) {
            *(float2*)(s1cc + ((size_t)row << 4) + n * 2) =
                make_float2(vv, m * (1.f / 127.f));
        } else {
            s1d[(size_t)row * 8 + (n - 8)] = vv;
        }
    }
}

// ---------------- GEMM2 worker: out1b[16,256] @ W2 -> biased-u8 h2i rows ---
// h2i row (64B): bytes 0..39 = int8 cols (lane n owns cols 4n..4n+3, n<10),
// float2(score_src, scale) at +40.
static __device__ __forceinline__ void dev_gemm2(int slab,
                                                 const ushortT* __restrict__ X,
                                                 const ushortT* __restrict__ Bt,
                                                 const float* __restrict__ a2s,
                                                 const float* __restrict__ a2d,
                                                 ucharT* __restrict__ h2i,
                                                 float* __restrict__ s2d, int M) {
    int lane = threadIdx.x & 63;
    int r0 = slab * 16;
    if (r0 >= M) return;
    int n = lane & 15, q = lane >> 4;
    const ushortT* xrow = X + (size_t)(r0 + n) * 256 + q * 8;
    float4v acc[4];
    #pragma unroll
    for (int j = 0; j < 4; ++j) acc[j] = (float4v){0.f, 0.f, 0.f, 0.f};
    #pragma unroll
    for (int s = 0; s < 8; ++s) {
        short8 a = *(const short8*)(xrow + s * 32);
        #pragma unroll
        for (int j = 0; j < 4; ++j) {
            short8 b = *(const short8*)(Bt + (size_t)(j * 16 + n) * 256 + s * 32 + q * 8);
            acc[j] = __builtin_amdgcn_mfma_f32_16x16x32_bf16(a, b, acc[j], 0, 0, 0);
        }
    }
    bool vn = (n < 10);
    float asv[4], adv[4];
    #pragma unroll
    for (int j = 0; j < 4; ++j) {
        int c = 4 * n + j;
        asv[j] = vn ? a2s[c] * LOG2E : 0.f;
        adv[j] = vn ? a2d[c] * LOG2E : 0.f;
    }
    float us[4], ud[4], am[4];
    #pragma unroll
    for (int r = 0; r < 4; ++r) {
        us[r] = acc[0][r] * asv[0] + acc[1][r] * asv[1] +
                acc[2][r] * asv[2] + acc[3][r] * asv[3];
        ud[r] = acc[0][r] * adv[0] + acc[1][r] * adv[1] +
                acc[2][r] * adv[2] + acc[3][r] * adv[3];
        float m = 0.f;
        if (vn) {
            #pragma unroll
            for (int j = 0; j < 4; ++j) m = fmaxf(m, fabsf(acc[j][r]));
        }
        am[r] = m;
    }
    #pragma unroll
    for (int off = 1; off < 16; off <<= 1) {
        #pragma unroll
        for (int r = 0; r < 4; ++r) {
            us[r] += __shfl_xor(us[r], off, 64);
            ud[r] += __shfl_xor(ud[r], off, 64);
            am[r] = fmaxf(am[r], __shfl_xor(am[r], off, 64));
        }
    }
    #pragma unroll
    for (int r = 0; r < 4; ++r) {
        int row = r0 + q * 4 + r;
        float m = am[r];
        float si = (m > 0.f) ? 127.f / m : 0.f;
        if (vn) {
            uintT p4 = 0;
            #pragma unroll
            for (int j = 0; j < 4; ++j) {
                int qv = (int)rintf(acc[j][r] * si) + 128;   // biased uint8
                p4 |= ((uintT)(qv & 0xff)) << (8 * j);
            }
            *(uintT*)(h2i + (size_t)row * 64 + n * 4) = p4;
        }
        if (n == 0) {
            *(float2*)(h2i + (size_t)row * 64 + 40) =
                make_float2(us[r], m * (1.f / 127.f));
            s2d[row] = ud[r];
        }
    }
}

// ---------------- P1: per-block LDS histogram over buckets (+ gemm chunk) --
__global__ __launch_bounds__(256) void k_cnt_g1(const int* __restrict__ ei, int E,
                                                int* __restrict__ counts, int nbuck,
                                                const float* __restrict__ A,
                                                const ushortT* __restrict__ Bt,
                                                ucharT* __restrict__ h1i,
                                                float* __restrict__ s1cc,
                                                float* __restrict__ s1d,
                                                int M, int nPrim, int slabBase) {
    if (blockIdx.x >= nPrim) {
        int wave = threadIdx.x >> 6;
        int slab = slabBase + (blockIdx.x - nPrim) * 4 + wave;
        dev_gemm1(slab, A, Bt, h1i, s1cc, s1d, M);
        return;
    }
    __shared__ int h[1024];
    int t = threadIdx.x;
    for (int i = t; i < nbuck; i += 256) h[i] = 0;
    __syncthreads();
    int base = blockIdx.x * EPB;
    #pragma unroll
    for (int r = 0; r < 4; ++r) {
        int i4 = base + (r * 256 + t) * 4;
        if (i4 + 3 < E) {
            int4 d = *(const int4*)(ei + E + i4);
            atomicAdd(&h[d.x >> 7], 1);
            atomicAdd(&h[d.y >> 7], 1);
            atomicAdd(&h[d.z >> 7], 1);
            atomicAdd(&h[d.w >> 7], 1);
        } else {
            for (int j = i4; j < E; ++j) atomicAdd(&h[ei[E + j] >> 7], 1);
        }
    }
    __syncthreads();
    int* crow = counts + (size_t)blockIdx.x * nbuck;
    for (int i = t; i < nbuck; i += 256) crow[i] = h[i];
}

// ---------------- P2: per-bucket exclusive scan across blocks --------------
__global__ __launch_bounds__(256) void k_scan_cols(int* __restrict__ counts,
                                                   int* __restrict__ totals,
                                                   int nb1, int nbuck) {
    __shared__ int wsum[4];
    int k = blockIdx.x;
    int t = threadIdx.x, lane = t & 63, wv = t >> 6;
    int e0 = 2 * t, e1 = 2 * t + 1;
    int v0 = (e0 < nb1) ? counts[(size_t)e0 * nbuck + k] : 0;
    int v1 = (e1 < nb1) ? counts[(size_t)e1 * nbuck + k] : 0;
    int s = v0 + v1;
    int incl = s;
    #pragma unroll
    for (int off = 1; off < 64; off <<= 1) {
        int u = __shfl_up(incl, off, 64);
        if (lane >= off) incl += u;
    }
    if (lane == 63) wsum[wv] = incl;
    __syncthreads();
    int add = 0;
    if (wv > 0) add += wsum[0];
    if (wv > 1) add += wsum[1];
    if (wv > 2) add += wsum[2];
    incl += add;
    int excl = incl - s;
    if (e0 < nb1) counts[(size_t)e0 * nbuck + k] = excl;
    if (e1 < nb1) counts[(size_t)e1 * nbuck + k] = excl + v0;
    if (t == 255) totals[k] = incl;
}

// ---------------- P3: bucket-contiguous placement (+ gemm chunk) -----------
__global__ __launch_bounds__(256) void k_place_g1(const int* __restrict__ ei, int E,
                                                  const int* __restrict__ counts,
                                                  const int* __restrict__ totals,
                                                  int* __restrict__ bstart,
                                                  uintT* __restrict__ tmp, int nbuck,
                                                  const float* __restrict__ A,
                                                  const ushortT* __restrict__ Bt,
                                                  ucharT* __restrict__ h1i,
                                                  float* __restrict__ s1cc,
                                                  float* __restrict__ s1d,
                                                  int M, int nPrim, int slabBase) {
    if (blockIdx.x >= nPrim) {
        int wave = threadIdx.x >> 6;
        int slab = slabBase + (blockIdx.x - nPrim) * 4 + wave;
        dev_gemm1(slab, A, Bt, h1i, s1cc, s1d, M);
        return;
    }
    __shared__ int st[1024];
    __shared__ int pos[1024];
    __shared__ int wsum[4];
    int t = threadIdx.x, lane = t & 63, wv = t >> 6;
    int b = blockIdx.x;
    int g[4];
    int s = 0;
    #pragma unroll
    for (int j = 0; j < 4; ++j) {
        int e = 4 * t + j;
        g[j] = (e < nbuck) ? totals[e] : 0;
        s += g[j];
    }
    int incl = s;
    #pragma unroll
    for (int off = 1; off < 64; off <<= 1) {
        int u = __shfl_up(incl, off, 64);
        if (lane >= off) incl += u;
    }
    if (lane == 63) wsum[wv] = incl;
    __syncthreads();
    int add = 0;
    if (wv > 0) add += wsum[0];
    if (wv > 1) add += wsum[1];
    if (wv > 2) add += wsum[2];
    int excl = incl + add - s;
    #pragma unroll
    for (int j = 0; j < 4; ++j) {
        int e = 4 * t + j;
        if (e < nbuck) st[e] = excl;
        excl += g[j];
    }
    __syncthreads();
    const int* crow = counts + (size_t)b * nbuck;
    for (int i = t; i < nbuck; i += 256) {
        int sv = st[i];
        pos[i] = sv + crow[i];
        if (b == 0) bstart[i] = sv;
    }
    __syncthreads();
    int base = b * EPB;
    #pragma unroll
    for (int r = 0; r < 4; ++r) {
        int i4 = base + (r * 256 + t) * 4;
        if (i4 + 3 < E) {
            int4 sv = *(const int4*)(ei + i4);
            int4 dv = *(const int4*)(ei + E + i4);
            int p0 = atomicAdd(&pos[dv.x >> 7], 1);
            tmp[p0] = (uintT)sv.x | (((uintT)dv.x & 127u) << 17);
            int p1 = atomicAdd(&pos[dv.y >> 7], 1);
            tmp[p1] = (uintT)sv.y | (((uintT)dv.y & 127u) << 17);
            int p2 = atomicAdd(&pos[dv.z >> 7], 1);
            tmp[p2] = (uintT)sv.z | (((uintT)dv.z & 127u) << 17);
            int p3 = atomicAdd(&pos[dv.w >> 7], 1);
            tmp[p3] = (uintT)sv.w | (((uintT)dv.w & 127u) << 17);
        } else {
            for (int j = i4; j < E; ++j) {
                int sj = ei[j], dj = ei[E + j];
                int p = atomicAdd(&pos[dj >> 7], 1);
                tmp[p] = (uintT)sj | (((uintT)dj & 127u) << 17);
            }
        }
    }
}

// ---------------- P4 worker: per-bucket CSR finalize ------------------------
static __device__ __forceinline__ void dev_csr(int k,
                                               const uintT* __restrict__ tmp,
                                               const int* __restrict__ bstart,
                                               const int* __restrict__ totals,
                                               int* __restrict__ rowptr,
                                               int* __restrict__ csr_src,
                                               int N, int* cnt, int* cur,
                                               int* wtot) {
    int t = threadIdx.x;
    int nodeBase = k << 7;
    int nn = N - nodeBase;
    if (nn > 128) nn = 128;
    int myStart = bstart[k];
    int myCount = totals[k];
    int csrBase = myStart + nodeBase;   // + self loops of preceding nodes
    if (t < 128) cnt[t] = 0;
    __syncthreads();
    for (int i = t; i < myCount; i += 256) {
        uintT p = tmp[myStart + i];
        atomicAdd(&cnt[p >> 17], 1);
    }
    __syncthreads();
    int dseg = 0, incl = 0;
    if (t < 128) {
        dseg = (t < nn) ? cnt[t] + 1 : 0;   // +1 self loop
        incl = dseg;
        #pragma unroll
        for (int off = 1; off < 64; off <<= 1) {
            int u = __shfl_up(incl, off, 64);
            if ((t & 63) >= off) incl += u;
        }
        if (t == 63) *wtot = incl;
    }
    __syncthreads();
    if (t < nn) {
        int excl = incl - dseg + ((t >= 64) ? *wtot : 0);
        int rp = csrBase + excl;
        int node = nodeBase + t;
        rowptr[node + 1] = rp + dseg;
        csr_src[rp] = node;              // self loop first
        cur[t] = rp + 1;
    }
    if (k == 0 && t == 0) rowptr[0] = 0;
    __syncthreads();
    for (int i = t; i < myCount; i += 256) {
        uintT p = tmp[myStart + i];
        int ld = p >> 17;
        int q = atomicAdd(&cur[ld], 1);
        csr_src[q] = (int)(p & 0x1FFFFu);
    }
}

// ---------------- P4a: buckets [0, nPrim) (+ gemm chunk) -------------------
__global__ __launch_bounds__(256) void k_csr_g1(const uintT* __restrict__ tmp,
                                                const int* __restrict__ bstart,
                                                const int* __restrict__ totals,
                                                int* __restrict__ rowptr,
                                                int* __restrict__ csr_src,
                                                int N,
                                                const float* __restrict__ A,
                                                const ushortT* __restrict__ Bt,
                                                ucharT* __restrict__ h1i,
                                                float* __restrict__ s1cc,
                                                float* __restrict__ s1d,
                                                int M, int nPrim, int slabBase) {
    __shared__ int cnt[128];
    __shared__ int cur[128];
    __shared__ int wtot;
    if (blockIdx.x >= nPrim) {
        int wave = threadIdx.x >> 6;
        int slab = slabBase + (blockIdx.x - nPrim) * 4 + wave;
        dev_gemm1(slab, A, Bt, h1i, s1cc, s1d, M);
        return;
    }
    dev_csr(blockIdx.x, tmp, bstart, totals, rowptr, csr_src, N, cnt, cur, &wtot);
}

// ---------------- layer-1 aggregation worker (2 nodes/wave) -----------------
struct Edge1 {
    float2 svc;       // (score_head, row scale)
    uint4 v;
    int si;
};

static __device__ __forceinline__ void ldi1(Edge1& S, int j, int endm1,
                                            const int* __restrict__ csr_src) {
    int jj = j < endm1 ? j : endm1;
    S.si = csr_src[jj];
}

static __device__ __forceinline__ void ldv1(Edge1& S, int j, int end,
                                            const float2* __restrict__ sc2,
                                            const ucharT* __restrict__ hb, int head) {
    if (j < end) {
        int s = S.si;
        S.svc = sc2[((size_t)s << 3) + head];
        S.v = *(const uint4*)(hb + ((size_t)s << 8));
    }
}

static __device__ __forceinline__ void ac1(const Edge1& S, float sdn,
                                           float2v* A, float& l, float& sps) {
    float p = exp2f(lrelu(S.svc.x + sdn));   // scores pre-scaled by log2e
    l += p;
    float ps = p * S.svc.y;
    sps += ps;
    float2v p2 = {ps, ps};
    uintT w;
    w = S.v.x;
    A[0] += p2 * (float2v){ub(w, 0), ub(w, 1)};
    A[1] += p2 * (float2v){ub(w, 2), ub(w, 3)};
    w = S.v.y;
    A[2] += p2 * (float2v){ub(w, 0), ub(w, 1)};
    A[3] += p2 * (float2v){ub(w, 2), ub(w, 3)};
    w = S.v.z;
    A[4] += p2 * (float2v){ub(w, 0), ub(w, 1)};
    A[5] += p2 * (float2v){ub(w, 2), ub(w, 3)};
    w = S.v.w;
    A[6] += p2 * (float2v){ub(w, 0), ub(w, 1)};
    A[7] += p2 * (float2v){ub(w, 2), ub(w, 3)};
}

static __device__ __forceinline__ void dev_agg1_pair(int n0, int NN,
                                                     const ucharT* __restrict__ h1i,
                                                     const float* __restrict__ s1cc,
                                                     const float* __restrict__ s1d,
                                                     const int* __restrict__ rowptr,
                                                     const int* __restrict__ csr_src,
                                                     const float* __restrict__ b1,
                                                     ushortT* __restrict__ out1) {
    int lane = threadIdx.x & 63;
    int half = lane >> 5;
    int n = n0 + half;
    bool act = n < NN;
    int l32 = lane & 31;
    int g = l32 >> 4;            // 2 edge slots per half
    int cl = l32 & 15;           // 16 channels each
    int head = cl >> 1;
    int beg = 0, end = 0;
    if (act) {
        beg = rowptr[n];
        end = rowptr[n + 1];
    }
    float sdn = act ? s1d[(size_t)n * 8 + head] : 0.f;
    const ucharT* hb = h1i + cl * 16;
    const float2* sc2 = (const float2*)s1cc;
    float2v A[8];
    #pragma unroll
    for (int k = 0; k < 8; ++k) A[k] = (float2v){0.f, 0.f};
    float l = 0.f, sps = 0.f;
    int i0 = beg + g;
    if (i0 < end) {
        int endm1 = end - 1;
        Edge1 S0, S1, S2;
        S0.svc = S1.svc = S2.svc = make_float2(0.f, 0.f);
        S0.v = S1.v = S2.v = make_uint4(0u, 0u, 0u, 0u);
        ldi1(S0, i0, endm1, csr_src);
        ldi1(S1, i0 + 2, endm1, csr_src);
        ldi1(S2, i0 + 4, endm1, csr_src);
        ldv1(S0, i0, end, sc2, hb, head);
        ldv1(S1, i0 + 2, end, sc2, hb, head);
        ldv1(S2, i0 + 4, end, sc2, hb, head);
        ldi1(S0, i0 + 6, endm1, csr_src);
        ldi1(S1, i0 + 8, endm1, csr_src);
        ldi1(S2, i0 + 10, endm1, csr_src);
        for (int idx = i0; idx < end; idx += 6) {
            ac1(S0, sdn, A, l, sps);
            ldv1(S0, idx + 6, end, sc2, hb, head);
            ldi1(S0, idx + 12, endm1, csr_src);
            if (idx + 2 < end) {
                ac1(S1, sdn, A, l, sps);
                ldv1(S1, idx + 8, end, sc2, hb, head);
                ldi1(S1, idx + 14, endm1, csr_src);
            }
            if (idx + 4 < end) {
                ac1(S2, sdn, A, l, sps);
                ldv1(S2, idx + 10, end, sc2, hb, head);
                ldi1(S2, idx + 16, endm1, csr_src);
            }
        }
    }
    // reduce across the 2 slots (xor-16 stays inside the 32-lane half)
    l += __shfl_xor(l, 16, 64);
    sps += __shfl_xor(sps, 16, 64);
    #pragma unroll
    for (int k = 0; k < 8; ++k) {
        A[k].x += __shfl_xor(A[k].x, 16, 64);
        A[k].y += __shfl_xor(A[k].y, 16, 64);
    }
    if (g == 0 && act) {
        float inv = 1.f / l;
        float adj = 128.f * sps;            // undo the uint8 bias
        const float4 bb0 = *(const float4*)(b1 + cl * 16);
        const float4 bb1 = *(const float4*)(b1 + cl * 16 + 4);
        const float4 bb2 = *(const float4*)(b1 + cl * 16 + 8);
        const float4 bb3 = *(const float4*)(b1 + cl * 16 + 12);
        float bbf[16] = {bb0.x, bb0.y, bb0.z, bb0.w, bb1.x, bb1.y, bb1.z, bb1.w,
                         bb2.x, bb2.y, bb2.z, bb2.w, bb3.x, bb3.y, bb3.z, bb3.w};
        uintT o[8];
        #pragma unroll
        for (int k = 0; k < 8; ++k) {
            float x0 = fmaxf((A[k].x - adj) * inv + bbf[2 * k], 0.f);
            float x1 = fmaxf((A[k].y - adj) * inv + bbf[2 * k + 1], 0.f);
            o[k] = pk(x0, x1);
        }
        *(uint4*)(out1 + (size_t)n * 256 + cl * 16) =
            make_uint4(o[0], o[1], o[2], o[3]);
        *(uint4*)(out1 + (size_t)n * 256 + cl * 16 + 8) =
            make_uint4(o[4], o[5], o[6], o[7]);
    }
}

// ---------------- fused: P4b (buckets >= halfB) ∥ agg1 nodes [0, H) --------
__global__ __launch_bounds__(256) void k_csr_agg1(const uintT* __restrict__ tmp,
                                                  const int* __restrict__ bstart,
                                                  const int* __restrict__ totals,
                                                  int* __restrict__ rowptr,
                                                  int* __restrict__ csr_src,
                                                  int N, int halfB, int nP4,
                                                  const ucharT* __restrict__ h1i,
                                                  const float* __restrict__ s1cc,
                                                  const float* __restrict__ s1d,
                                                  const float* __restrict__ b1,
                                                  ushortT* __restrict__ out1, int H) {
    __shared__ int cnt[128];
    __shared__ int cur[128];
    __shared__ int wtot;
    if (blockIdx.x < nP4) {
        dev_csr(halfB + blockIdx.x, tmp, bstart, totals, rowptr, csr_src, N,
                cnt, cur, &wtot);
        return;
    }
    int n0 = (blockIdx.x - nP4) * 8 + (threadIdx.x >> 6) * 2;
    if (n0 >= H) return;
    dev_agg1_pair(n0, H, h1i, s1cc, s1d, rowptr, csr_src, b1, out1);
}

// ---------------- fused: agg1 nodes [H, N) ∥ gemm2 rows [0, H) -------------
__global__ __launch_bounds__(256) void k_agg1_g2(const ucharT* __restrict__ h1i,
                                                 const float* __restrict__ s1cc,
                                                 const float* __restrict__ s1d,
                                                 const int* __restrict__ rowptr,
                                                 const int* __restrict__ csr_src,
                                                 const float* __restrict__ b1,
                                                 ushortT* __restrict__ out1,
                                                 int base, int N, int nAgg,
                                                 const ushortT* __restrict__ X,
                                                 const ushortT* __restrict__ Bt2,
                                                 const float* __restrict__ a2s,
                                                 const float* __restrict__ a2d,
                                                 ucharT* __restrict__ h2i,
                                                 float* __restrict__ s2d, int MG2) {
    if (blockIdx.x >= nAgg) {
        int wave = threadIdx.x >> 6;
        int slab = (blockIdx.x - nAgg) * 4 + wave;
        dev_gemm2(slab, X, Bt2, a2s, a2d, h2i, s2d, MG2);
        return;
    }
    int n0 = base + blockIdx.x * 8 + (threadIdx.x >> 6) * 2;
    if (n0 >= N) return;
    dev_agg1_pair(n0, N, h1i, s1cc, s1d, rowptr, csr_src, b1, out1);
}

// ---------------- GEMM2 remainder: rows [H, N) -----------------------------
__global__ __launch_bounds__(256) void k_gemm2(const ushortT* __restrict__ X,
                                               const ushortT* __restrict__ Bt,
                                               const float* __restrict__ a2s,
                                               const float* __restrict__ a2d,
                                               ucharT* __restrict__ h2i,
                                               float* __restrict__ s2d,
                                               int slabBase, int M) {
    int wave = threadIdx.x >> 6;
    int slab = slabBase + blockIdx.x * 4 + wave;
    dev_gemm2(slab, X, Bt, a2s, a2d, h2i, s2d, M);
}

// ---------------- layer-2 aggregation + log_softmax (2 nodes/wave) ---------
// Per 32-lane half: one node, 3 slots x 10 ch-lanes (4 int8 ch each).
struct Edge2 {
    float2 svc;       // (score_src, row scale)
    uintT v;
    int si;
};

static __device__ __forceinline__ void ldi2(Edge2& S, int j, int endm1,
                                            const int* __restrict__ csr_src) {
    int jj = j < endm1 ? j : endm1;
    S.si = csr_src[jj];
}

static __device__ __forceinline__ void ldv2(Edge2& S, int j, int end,
                                            const ucharT* __restrict__ h2i, int cl) {
    if (j < end) {
        const ucharT* hr = h2i + (size_t)S.si * 64;
        S.v = *(const uintT*)(hr + cl * 4);
        S.svc = *(const float2*)(hr + 40);
    }
}

static __device__ __forceinline__ void ac2(const Edge2& S, float sdn,
                                           float2v& A01, float2v& A23,
                                           float& l, float& sps) {
    float p = exp2f(lrelu(S.svc.x + sdn));   // pre-scaled scores
    l += p;
    float ps = p * S.svc.y;
    sps += ps;
    float2v p2 = {ps, ps};
    A01 += p2 * (float2v){ub(S.v, 0), ub(S.v, 1)};
    A23 += p2 * (float2v){ub(S.v, 2), ub(S.v, 3)};
}

__global__ __launch_bounds__(256) void k_agg2lsm(const ucharT* __restrict__ h2i,
                                                 const float* __restrict__ sd,
                                                 const int* __restrict__ rowptr,
                                                 const int* __restrict__ csr_src,
                                                 const float* __restrict__ b2,
                                                 float* __restrict__ out, int N) {
    int lane = threadIdx.x & 63;
    int half = lane >> 5;
    int l32 = lane & 31;
    int n = blockIdx.x * 8 + (threadIdx.x >> 6) * 2 + half;
    bool act = n < N;
    int el = l32 / 10;           // 0..3 (l32 30,31 idle)
    int cl = l32 - el * 10;      // 10 ch-lanes x 4 int8 channels
    int beg = 0, end = 0;
    if (act) {
        beg = rowptr[n];
        end = rowptr[n + 1];
    }
    float sdn = act ? sd[n] : 0.f;
    float2v A01 = (float2v){0.f, 0.f}, A23 = (float2v){0.f, 0.f};
    float l = 0.f, sps = 0.f;
    if (el < 3) {
        int i0 = beg + el;
        if (i0 < end) {
            int endm1 = end - 1;
            Edge2 S0, S1, S2;
            S0.svc = S1.svc = S2.svc = make_float2(0.f, 0.f);
            S0.v = S1.v = S2.v = 0u;
            ldi2(S0, i0, endm1, csr_src);
            ldi2(S1, i0 + 3, endm1, csr_src);
            ldi2(S2, i0 + 6, endm1, csr_src);
            ldv2(S0, i0, end, h2i, cl);
            ldv2(S1, i0 + 3, end, h2i, cl);
            ldv2(S2, i0 + 6, end, h2i, cl);
            ldi2(S0, i0 + 9, endm1, csr_src);
            ldi2(S1, i0 + 12, endm1, csr_src);
            ldi2(S2, i0 + 15, endm1, csr_src);
            for (int idx = i0; idx < end; idx += 9) {
                ac2(S0, sdn, A01, A23, l, sps);
                ldv2(S0, idx + 9, end, h2i, cl);
                ldi2(S0, idx + 18, endm1, csr_src);
                if (idx + 3 < end) {
                    ac2(S1, sdn, A01, A23, l, sps);
                    ldv2(S1, idx + 12, end, h2i, cl);
                    ldi2(S1, idx + 21, endm1, csr_src);
                }
                if (idx + 6 < end) {
                    ac2(S2, sdn, A01, A23, l, sps);
                    ldv2(S2, idx + 15, end, h2i, cl);
                    ldi2(S2, idx + 24, endm1, csr_src);
                }
            }
        }
    }
    float a0 = A01.x, a1 = A01.y, a2 = A23.x, a3 = A23.y;
    // fold slots 1,2 -> slot 0 within each half (valid on el==0 lanes)
    int base = lane & 32;
    int f1 = base + cl + 10, f2 = base + cl + 20;
    a0 += __shfl(a0, f1, 64) + __shfl(a0, f2, 64);
    a1 += __shfl(a1, f1, 64) + __shfl(a1, f2, 64);
    a2 += __shfl(a2, f1, 64) + __shfl(a2, f2, 64);
    a3 += __shfl(a3, f1, 64) + __shfl(a3, f2, 64);
    l  += __shfl(l, f1, 64) + __shfl(l, f2, 64);
    sps += __shfl(sps, f1, 64) + __shfl(sps, f2, 64);
    float inv = 1.f / l;
    float adj = 128.f * sps;            // undo the uint8 bias
    float4 bb = *(const float4*)(b2 + cl * 4);
    float o0 = (a0 - adj) * inv + bb.x;
    float o1 = (a1 - adj) * inv + bb.y;
    float o2 = (a2 - adj) * inv + bb.z;
    float o3 = (a3 - adj) * inv + bb.w;
    bool valid = (el == 0);             // l32 < 10
    float lm = valid ? fmaxf(fmaxf(o0, o1), fmaxf(o2, o3)) : -INFINITY;
    #pragma unroll
    for (int off = 16; off; off >>= 1) lm = fmaxf(lm, __shfl_xor(lm, off, 64));
    float le = valid
        ? __expf(o0 - lm) + __expf(o1 - lm) + __expf(o2 - lm) + __expf(o3 - lm)
        : 0.f;
    #pragma unroll
    for (int off = 16; off; off >>= 1) le += __shfl_xor(le, off, 64);
    float ls = lm + logf(le);
    if (valid && act) {
        float4 w = make_float4(o0 - ls, o1 - ls, o2 - ls, o3 - ls);
        *(float4*)(out + (size_t)n * 40 + cl * 4) = w;
    }
}

// ---------------------------------------------------------------------------
extern "C" void kernel_launch(void* const* d_in, const int* in_sizes, int n_in,
                              void* d_out, int out_size, void* d_ws, size_t ws_size,
                              hipStream_t stream) {
    const float* x   = (const float*)d_in[0];
    const int*   ei  = (const int*)d_in[1];
    const float* W1  = (const float*)d_in[2];
    const float* a1s = (const float*)d_in[3];
    const float* a1d = (const float*)d_in[4];
    const float* b1  = (const float*)d_in[5];
    const float* W2  = (const float*)d_in[6];
    const float* a2s = (const float*)d_in[7];
    const float* a2d = (const float*)d_in[8];
    const float* b2  = (const float*)d_in[9];
    float* out = (float*)d_out;

    const int N = in_sizes[0] / 128;   // 100000
    const int E = in_sizes[1] / 2;     // 1600000
    const int ET = E + N;
    const int NBUCK = (N + 127) >> 7;              // 782
    const int NB1 = (E + EPB - 1) / EPB;           // 391

    // ---- workspace layout ----
    char* w = (char*)d_ws;
    ucharT* h1i = (ucharT*)w;                             // N*256 u8 (25.6 MB)
    ushortT* out1b = (ushortT*)(w + (size_t)N * 256);     // N*256 bf16 (51.2 MB)
    int* i_row = (int*)(w + (size_t)N * 768);             // N+16 ints
    float* s1cc = (float*)(w + (size_t)N * 768 + ((size_t)N + 16) * 4); // N*16 f32
    float* s1d = s1cc + (size_t)N * 16;                   // N*8 f32
    int* i_cnt = (int*)(s1d + (size_t)N * 8);             // NB1*NBUCK
    int* i_tot = i_cnt + (size_t)NB1 * NBUCK;             // NBUCK+2
    int* i_bst = i_tot + NBUCK + 2;                       // NBUCK+2
    // i_tmp aligned UP to 64B so the h2i overlay starts exactly at i_tmp
    // (alignment-independent of d_ws base; no intrusion into i_bst).
    uintT* i_tmp = (uintT*)(((uintptr_t)(i_bst + NBUCK + 2) + 63) &
                            ~(uintptr_t)63);              // E packed pairs
    int* i_csr = (int*)(i_tmp + E);                       // ET ints
    ushortT* W1t = (ushortT*)(i_csr + ET);                // 272*128 bf16
    ushortT* W2t = W1t + 272 * 128;                       // 64*256 bf16
    // layer-2 overlays (dead after P4 / P3):
    //   h2i: N*64 B == E*4 B, exactly over i_tmp (64B-aligned).
    //   s2d (N f32) over i_cnt (dead after P3).
    ucharT* h2i = (ucharT*)i_tmp;
    float* s2d = (float*)i_cnt;

    const int nbG = (N / 16 + 3) / 4;            // gemm1 blocks (4 waves x 16 rows)
    const int CH  = (nbG + 2) / 3;               // gemm1 chunk (blocks)
    const int halfB = NBUCK >> 1;                // 391
    const int H = halfB << 7;                    // 50048 nodes in first half
    const int nP4b = NBUCK - halfB;              // 391
    const int nAgg1a = (H + 7) / 8;              // agg1 pair blocks, first half
    const int nAgg1b = (N - H + 7) / 8;          // agg1 pair blocks, tail
    const int g2aSlabs = H / 16;                 // 3128 (H multiple of 16)
    const int g2aBlocks = g2aSlabs / 4;          // 782
    const int nSlab = (N + 15) / 16;             // 6250
    const int g2bBlocks = (nSlab - g2aSlabs + 3) / 4;   // 781
    const int nb8 = (N + 7) / 8;                 // agg2 blocks (8 nodes each)

    // ---- L0: weight prep ----
    k_prep<<<PREP_BLOCKS, 256, 0, stream>>>(W1, W2, a1s, a1d, W1t, W2t);
    // ---- P1: bucket histogram ∥ gemm1 chunk 0 ----
    k_cnt_g1<<<NB1 + CH, 256, 0, stream>>>(ei, E, i_cnt, NBUCK,
                                           x, W1t, h1i, s1cc, s1d,
                                           N, NB1, 0);
    // ---- P2: per-bucket scan across blocks ----
    k_scan_cols<<<NBUCK, 256, 0, stream>>>(i_cnt, i_tot, NB1, NBUCK);
    // ---- P3: bucket-contiguous placement ∥ gemm1 chunk 1 ----
    k_place_g1<<<NB1 + CH, 256, 0, stream>>>(ei, E, i_cnt, i_tot, i_bst, i_tmp, NBUCK,
                                             x, W1t, h1i, s1cc, s1d,
                                             N, NB1, CH * 4);
    // ---- P4a: CSR finalize buckets [0, halfB) ∥ gemm1 chunk 2 ----
    k_csr_g1<<<halfB + CH, 256, 0, stream>>>(i_tmp, i_bst, i_tot, i_row, i_csr, N,
                                             x, W1t, h1i, s1cc, s1d,
                                             N, halfB, CH * 8);
    // ---- P4b ∥ agg1 nodes [0, H) ----
    k_csr_agg1<<<nP4b + nAgg1a, 256, 0, stream>>>(i_tmp, i_bst, i_tot, i_row, i_csr,
                                                  N, halfB, nP4b,
                                                  h1i, s1cc, s1d, b1, out1b, H);
    // ---- agg1 tail nodes [H, N) ∥ gemm2 rows [0, H) ----
    k_agg1_g2<<<nAgg1b + g2aBlocks, 256, 0, stream>>>(h1i, s1cc, s1d, i_row, i_csr,
                                                      b1, out1b, H, N, nAgg1b,
                                                      out1b, W2t, a2s, a2d,
                                                      h2i, s2d, H);
    // ---- gemm2 remainder rows [H, N) ----
    k_gemm2<<<g2bBlocks, 256, 0, stream>>>(out1b, W2t, a2s, a2d, h2i, s2d,
                                           g2aSlabs, N);
    // ---- layer-2 aggregation + log_softmax ----
    k_agg2lsm<<<nb8, 256, 0, stream>>>(h2i, s2d, i_row, i_csr, b2, out, N);
}

// Round 11
// 386.447 us; speedup vs baseline: 1.0536x; 1.0263x over previous
//
#include <hip/hip_runtime.h>
#include <hip/hip_bf16.h>
#include <cmath>

// ---------------------------------------------------------------------------
// GAT 2-layer forward.
//  - LDS-free MFMA GEMMs (A direct global->reg, B pre-transposed bf16).
//  - scores1 fused into GEMM1 (extra 16 cols via Wa = W1 @ blockdiag(a)),
//    Wa PRE-SCALED by log2e -> agg kernels use exp2f (bare v_exp_f32).
//  - h1 stored BIASED UINT8 (q+128) with per-row scale; agg1 unpacks with
//    v_cvt_f32_ubyte{0..3}, corrected by 128*sum(p*scale) in the epilogue.
//  - s1cc[node][head] = float2(score_h, scale): 64B-aligned records.
//  - agg1: TWO NODES PER WAVE (32-lane halves), 2 slots x 16 ch-lanes each.
//  - h2 ALSO biased int8: 64-byte rows = 40 int8 + float2(score,scale) at +40;
//    ONE cache line per edge in agg2. Table overlays dead i_tmp (64B-aligned).
//  - agg2: TWO NODES PER WAVE (3 slots x 10 ch-lanes per half), staged fold.
//  - Two-level rotation-free 3x pipelines (index 1 rotation ahead).
//  - CSR build WITHOUT global atomics (bucketed counting sort P1..P4).
//  - LPT grid ordering: long MFMA gemm blocks FIRST in every fused grid
//    (gemm1 chunks before P1/P3/P4a work; gemm2a before agg1 tail) so the
//    dispatch drains through short gather blocks, not an MFMA tail.
//  - Bucket split halfB = 9/16 NBUCK to balance K1 (P4b∥agg1a) vs
//    K2 (gemm2a∥agg1b).
//  - log_softmax fused into agg2.
// ---------------------------------------------------------------------------

typedef unsigned short ushortT;
typedef unsigned int uintT;
typedef unsigned char ucharT;
typedef __attribute__((ext_vector_type(8))) short short8;
typedef __attribute__((ext_vector_type(4))) float float4v;
typedef __attribute__((ext_vector_type(2))) float float2v;

#define LOG2E 1.4426950408889634f

static __device__ __forceinline__ ushortT f2bf(float f) {
    __hip_bfloat16 h = __float2bfloat16(f);   // RNE
    return *reinterpret_cast<ushortT*>(&h);
}
static __device__ __forceinline__ uintT pk(float a, float b) {
    return (uintT)f2bf(a) | ((uintT)f2bf(b) << 16);
}
static __device__ __forceinline__ float ub(uintT u, int k) {   // unsigned byte k
    return (float)((u >> (8 * k)) & 0xffu);                    // -> v_cvt_f32_ubyteN
}
// leaky: e>=0 -> e ; e<0 -> 0.2e.  0.6e + 0.4|e| (2 VALU, abs = modifier)
static __device__ __forceinline__ float lrelu(float e) {
    return 0.6f * e + 0.4f * fabsf(e);
}

#define PREP_BLOCKS 200
#define EPB 4096              // edges per histogram/placement block

// ---------------- prep: transpose weights to bf16 + score matrix -----------
// W2t: 64 x 256, storage row s=(j<<4)|n holds ORIGINAL col 4n+j (n<10).
__global__ __launch_bounds__(256) void k_prep(const float* __restrict__ W1,
                                              const float* __restrict__ W2,
                                              const float* __restrict__ a1s,
                                              const float* __restrict__ a1d,
                                              ushortT* __restrict__ W1t,
                                              ushortT* __restrict__ W2t) {
    int t = blockIdx.x * 256 + threadIdx.x;
    if (t < 128 * 256) {
        int k = t >> 8, s = t & 255;
        int c = ((s & 15) << 4) | (s >> 4);
        W1t[s * 128 + k] = f2bf(W1[(size_t)k * 256 + c]);
    } else if (t < 128 * 256 + 64 * 256) {
        int q = t - 128 * 256;
        int k = q >> 6, s = q & 63;
        int n = s & 15, j = s >> 4;
        int c = 4 * n + j;
        W2t[s * 256 + k] = (n < 10) ? f2bf(W2[k * 40 + c]) : (ushortT)0;
    } else if (t < 128 * 256 + 64 * 256 + 2048) {
        int q = t - (128 * 256 + 64 * 256);
        int k = q >> 4, j = q & 15;
        int h = j & 7;
        const float* av = ((j < 8) ? a1s : a1d) + h * 32;
        const float* wr = W1 + (size_t)k * 256 + h * 32;
        float s = 0.f;
        #pragma unroll
        for (int c = 0; c < 32; ++c) s += wr[c] * av[c];
        W1t[(256 + j) * 128 + k] = f2bf(s * LOG2E);   // pre-scaled for exp2
    }
}

// ---------------- GEMM1 worker: x[16,128] @ W1 -> biased-u8 h1i + s1cc/s1d -
static __device__ __forceinline__ void dev_gemm1(int slab,
                                                 const float* __restrict__ A,
                                                 const ushortT* __restrict__ Bt,
                                                 ucharT* __restrict__ h1i,
                                                 float* __restrict__ s1cc,
                                                 float* __restrict__ s1d, int M) {
    int lane = threadIdx.x & 63;
    int r0 = slab * 16;
    if (r0 >= M) return;
    int n = lane & 15, q = lane >> 4;
    const float* arow = A + (size_t)(r0 + n) * 128 + q * 8;
    short8 af[4];
    #pragma unroll
    for (int s = 0; s < 4; ++s) {
        float4 v0 = *(const float4*)(arow + s * 32);
        float4 v1 = *(const float4*)(arow + s * 32 + 4);
        short8 a;
        a[0] = (short)f2bf(v0.x); a[1] = (short)f2bf(v0.y);
        a[2] = (short)f2bf(v0.z); a[3] = (short)f2bf(v0.w);
        a[4] = (short)f2bf(v1.x); a[5] = (short)f2bf(v1.y);
        a[6] = (short)f2bf(v1.z); a[7] = (short)f2bf(v1.w);
        af[s] = a;
    }
    float4v acc[17];
    #pragma unroll
    for (int j = 0; j < 17; ++j) acc[j] = (float4v){0.f, 0.f, 0.f, 0.f};
    #pragma unroll
    for (int s = 0; s < 4; ++s) {
        #pragma unroll
        for (int j = 0; j < 17; ++j) {
            short8 b = *(const short8*)(Bt + (size_t)(j * 16 + n) * 128 + s * 32 + q * 8);
            acc[j] = __builtin_amdgcn_mfma_f32_16x16x32_bf16(af[s], b, acc[j], 0, 0, 0);
        }
    }
    float am[4];
    #pragma unroll
    for (int r = 0; r < 4; ++r) {
        float m = 0.f;
        #pragma unroll
        for (int j = 0; j < 16; ++j) m = fmaxf(m, fabsf(acc[j][r]));
        am[r] = m;
    }
    #pragma unroll
    for (int off = 1; off < 16; off <<= 1) {
        #pragma unroll
        for (int r = 0; r < 4; ++r) am[r] = fmaxf(am[r], __shfl_xor(am[r], off, 64));
    }
    #pragma unroll
    for (int r = 0; r < 4; ++r) {
        int row = r0 + q * 4 + r;
        float m = am[r];
        float si = (m > 0.f) ? 127.f / m : 0.f;
        uintT wd[4];
        #pragma unroll
        for (int wq = 0; wq < 4; ++wq) {
            uintT p4 = 0;
            #pragma unroll
            for (int b = 0; b < 4; ++b) {
                int j = wq * 4 + b;
                int qv = (int)rintf(acc[j][r] * si) + 128;   // biased uint8
                p4 |= ((uintT)(qv & 0xff)) << (8 * b);
            }
            wd[wq] = p4;
        }
        uint4 o = make_uint4(wd[0], wd[1], wd[2], wd[3]);
        *(uint4*)(h1i + (size_t)row * 256 + n * 16) = o;
        float vv = acc[16][r];
        if (n < 8) {
            *(float2*)(s1cc + ((size_t)row << 4) + n * 2) =
                make_float2(vv, m * (1.f / 127.f));
        } else {
            s1d[(size_t)row * 8 + (n - 8)] = vv;
        }
    }
}

// ---------------- GEMM2 worker: out1b[16,256] @ W2 -> biased-u8 h2i rows ---
// h2i row (64B): bytes 0..39 = int8 cols (lane n owns cols 4n..4n+3, n<10),
// float2(score_src, scale) at +40.
static __device__ __forceinline__ void dev_gemm2(int slab,
                                                 const ushortT* __restrict__ X,
                                                 const ushortT* __restrict__ Bt,
                                                 const float* __restrict__ a2s,
                                                 const float* __restrict__ a2d,
                                                 ucharT* __restrict__ h2i,
                                                 float* __restrict__ s2d, int M) {
    int lane = threadIdx.x & 63;
    int r0 = slab * 16;
    if (r0 >= M) return;
    int n = lane & 15, q = lane >> 4;
    const ushortT* xrow = X + (size_t)(r0 + n) * 256 + q * 8;
    float4v acc[4];
    #pragma unroll
    for (int j = 0; j < 4; ++j) acc[j] = (float4v){0.f, 0.f, 0.f, 0.f};
    #pragma unroll
    for (int s = 0; s < 8; ++s) {
        short8 a = *(const short8*)(xrow + s * 32);
        #pragma unroll
        for (int j = 0; j < 4; ++j) {
            short8 b = *(const short8*)(Bt + (size_t)(j * 16 + n) * 256 + s * 32 + q * 8);
            acc[j] = __builtin_amdgcn_mfma_f32_16x16x32_bf16(a, b, acc[j], 0, 0, 0);
        }
    }
    bool vn = (n < 10);
    float asv[4], adv[4];
    #pragma unroll
    for (int j = 0; j < 4; ++j) {
        int c = 4 * n + j;
        asv[j] = vn ? a2s[c] * LOG2E : 0.f;
        adv[j] = vn ? a2d[c] * LOG2E : 0.f;
    }
    float us[4], ud[4], am[4];
    #pragma unroll
    for (int r = 0; r < 4; ++r) {
        us[r] = acc[0][r] * asv[0] + acc[1][r] * asv[1] +
                acc[2][r] * asv[2] + acc[3][r] * asv[3];
        ud[r] = acc[0][r] * adv[0] + acc[1][r] * adv[1] +
                acc[2][r] * adv[2] + acc[3][r] * adv[3];
        float m = 0.f;
        if (vn) {
            #pragma unroll
            for (int j = 0; j < 4; ++j) m = fmaxf(m, fabsf(acc[j][r]));
        }
        am[r] = m;
    }
    #pragma unroll
    for (int off = 1; off < 16; off <<= 1) {
        #pragma unroll
        for (int r = 0; r < 4; ++r) {
            us[r] += __shfl_xor(us[r], off, 64);
            ud[r] += __shfl_xor(ud[r], off, 64);
            am[r] = fmaxf(am[r], __shfl_xor(am[r], off, 64));
        }
    }
    #pragma unroll
    for (int r = 0; r < 4; ++r) {
        int row = r0 + q * 4 + r;
        float m = am[r];
        float si = (m > 0.f) ? 127.f / m : 0.f;
        if (vn) {
            uintT p4 = 0;
            #pragma unroll
            for (int j = 0; j < 4; ++j) {
                int qv = (int)rintf(acc[j][r] * si) + 128;   // biased uint8
                p4 |= ((uintT)(qv & 0xff)) << (8 * j);
            }
            *(uintT*)(h2i + (size_t)row * 64 + n * 4) = p4;
        }
        if (n == 0) {
            *(float2*)(h2i + (size_t)row * 64 + 40) =
                make_float2(us[r], m * (1.f / 127.f));
            s2d[row] = ud[r];
        }
    }
}

// ---------------- P1: gemm1 chunk FIRST, then LDS bucket histogram ---------
__global__ __launch_bounds__(256) void k_cnt_g1(const int* __restrict__ ei, int E,
                                                int* __restrict__ counts, int nbuck,
                                                const float* __restrict__ A,
                                                const ushortT* __restrict__ Bt,
                                                ucharT* __restrict__ h1i,
                                                float* __restrict__ s1cc,
                                                float* __restrict__ s1d,
                                                int M, int nPrim, int slabBase) {
    int nG = gridDim.x - nPrim;
    if (blockIdx.x < nG) {
        int wave = threadIdx.x >> 6;
        int slab = slabBase + blockIdx.x * 4 + wave;
        dev_gemm1(slab, A, Bt, h1i, s1cc, s1d, M);
        return;
    }
    int b = blockIdx.x - nG;
    __shared__ int h[1024];
    int t = threadIdx.x;
    for (int i = t; i < nbuck; i += 256) h[i] = 0;
    __syncthreads();
    int base = b * EPB;
    #pragma unroll
    for (int r = 0; r < 4; ++r) {
        int i4 = base + (r * 256 + t) * 4;
        if (i4 + 3 < E) {
            int4 d = *(const int4*)(ei + E + i4);
            atomicAdd(&h[d.x >> 7], 1);
            atomicAdd(&h[d.y >> 7], 1);
            atomicAdd(&h[d.z >> 7], 1);
            atomicAdd(&h[d.w >> 7], 1);
        } else {
            for (int j = i4; j < E; ++j) atomicAdd(&h[ei[E + j] >> 7], 1);
        }
    }
    __syncthreads();
    int* crow = counts + (size_t)b * nbuck;
    for (int i = t; i < nbuck; i += 256) crow[i] = h[i];
}

// ---------------- P2: per-bucket exclusive scan across blocks --------------
__global__ __launch_bounds__(256) void k_scan_cols(int* __restrict__ counts,
                                                   int* __restrict__ totals,
                                                   int nb1, int nbuck) {
    __shared__ int wsum[4];
    int k = blockIdx.x;
    int t = threadIdx.x, lane = t & 63, wv = t >> 6;
    int e0 = 2 * t, e1 = 2 * t + 1;
    int v0 = (e0 < nb1) ? counts[(size_t)e0 * nbuck + k] : 0;
    int v1 = (e1 < nb1) ? counts[(size_t)e1 * nbuck + k] : 0;
    int s = v0 + v1;
    int incl = s;
    #pragma unroll
    for (int off = 1; off < 64; off <<= 1) {
        int u = __shfl_up(incl, off, 64);
        if (lane >= off) incl += u;
    }
    if (lane == 63) wsum[wv] = incl;
    __syncthreads();
    int add = 0;
    if (wv > 0) add += wsum[0];
    if (wv > 1) add += wsum[1];
    if (wv > 2) add += wsum[2];
    incl += add;
    int excl = incl - s;
    if (e0 < nb1) counts[(size_t)e0 * nbuck + k] = excl;
    if (e1 < nb1) counts[(size_t)e1 * nbuck + k] = excl + v0;
    if (t == 255) totals[k] = incl;
}

// ---------------- P3: gemm1 chunk FIRST, then bucket-contiguous placement --
__global__ __launch_bounds__(256) void k_place_g1(const int* __restrict__ ei, int E,
                                                  const int* __restrict__ counts,
                                                  const int* __restrict__ totals,
                                                  int* __restrict__ bstart,
                                                  uintT* __restrict__ tmp, int nbuck,
                                                  const float* __restrict__ A,
                                                  const ushortT* __restrict__ Bt,
                                                  ucharT* __restrict__ h1i,
                                                  float* __restrict__ s1cc,
                                                  float* __restrict__ s1d,
                                                  int M, int nPrim, int slabBase) {
    int nG = gridDim.x - nPrim;
    if (blockIdx.x < nG) {
        int wave = threadIdx.x >> 6;
        int slab = slabBase + blockIdx.x * 4 + wave;
        dev_gemm1(slab, A, Bt, h1i, s1cc, s1d, M);
        return;
    }
    int b = blockIdx.x - nG;
    __shared__ int st[1024];
    __shared__ int pos[1024];
    __shared__ int wsum[4];
    int t = threadIdx.x, lane = t & 63, wv = t >> 6;
    int g[4];
    int s = 0;
    #pragma unroll
    for (int j = 0; j < 4; ++j) {
        int e = 4 * t + j;
        g[j] = (e < nbuck) ? totals[e] : 0;
        s += g[j];
    }
    int incl = s;
    #pragma unroll
    for (int off = 1; off < 64; off <<= 1) {
        int u = __shfl_up(incl, off, 64);
        if (lane >= off) incl += u;
    }
    if (lane == 63) wsum[wv] = incl;
    __syncthreads();
    int add = 0;
    if (wv > 0) add += wsum[0];
    if (wv > 1) add += wsum[1];
    if (wv > 2) add += wsum[2];
    int excl = incl + add - s;
    #pragma unroll
    for (int j = 0; j < 4; ++j) {
        int e = 4 * t + j;
        if (e < nbuck) st[e] = excl;
        excl += g[j];
    }
    __syncthreads();
    const int* crow = counts + (size_t)b * nbuck;
    for (int i = t; i < nbuck; i += 256) {
        int sv = st[i];
        pos[i] = sv + crow[i];
        if (b == 0) bstart[i] = sv;
    }
    __syncthreads();
    int base = b * EPB;
    #pragma unroll
    for (int r = 0; r < 4; ++r) {
        int i4 = base + (r * 256 + t) * 4;
        if (i4 + 3 < E) {
            int4 sv = *(const int4*)(ei + i4);
            int4 dv = *(const int4*)(ei + E + i4);
            int p0 = atomicAdd(&pos[dv.x >> 7], 1);
            tmp[p0] = (uintT)sv.x | (((uintT)dv.x & 127u) << 17);
            int p1 = atomicAdd(&pos[dv.y >> 7], 1);
            tmp[p1] = (uintT)sv.y | (((uintT)dv.y & 127u) << 17);
            int p2 = atomicAdd(&pos[dv.z >> 7], 1);
            tmp[p2] = (uintT)sv.z | (((uintT)dv.z & 127u) << 17);
            int p3 = atomicAdd(&pos[dv.w >> 7], 1);
            tmp[p3] = (uintT)sv.w | (((uintT)dv.w & 127u) << 17);
        } else {
            for (int j = i4; j < E; ++j) {
                int sj = ei[j], dj = ei[E + j];
                int p = atomicAdd(&pos[dj >> 7], 1);
                tmp[p] = (uintT)sj | (((uintT)dj & 127u) << 17);
            }
        }
    }
}

// ---------------- P4 worker: per-bucket CSR finalize ------------------------
static __device__ __forceinline__ void dev_csr(int k,
                                               const uintT* __restrict__ tmp,
                                               const int* __restrict__ bstart,
                                               const int* __restrict__ totals,
                                               int* __restrict__ rowptr,
                                               int* __restrict__ csr_src,
                                               int N, int* cnt, int* cur,
                                               int* wtot) {
    int t = threadIdx.x;
    int nodeBase = k << 7;
    int nn = N - nodeBase;
    if (nn > 128) nn = 128;
    int myStart = bstart[k];
    int myCount = totals[k];
    int csrBase = myStart + nodeBase;   // + self loops of preceding nodes
    if (t < 128) cnt[t] = 0;
    __syncthreads();
    for (int i = t; i < myCount; i += 256) {
        uintT p = tmp[myStart + i];
        atomicAdd(&cnt[p >> 17], 1);
    }
    __syncthreads();
    int dseg = 0, incl = 0;
    if (t < 128) {
        dseg = (t < nn) ? cnt[t] + 1 : 0;   // +1 self loop
        incl = dseg;
        #pragma unroll
        for (int off = 1; off < 64; off <<= 1) {
            int u = __shfl_up(incl, off, 64);
            if ((t & 63) >= off) incl += u;
        }
        if (t == 63) *wtot = incl;
    }
    __syncthreads();
    if (t < nn) {
        int excl = incl - dseg + ((t >= 64) ? *wtot : 0);
        int rp = csrBase + excl;
        int node = nodeBase + t;
        rowptr[node + 1] = rp + dseg;
        csr_src[rp] = node;              // self loop first
        cur[t] = rp + 1;
    }
    if (k == 0 && t == 0) rowptr[0] = 0;
    __syncthreads();
    for (int i = t; i < myCount; i += 256) {
        uintT p = tmp[myStart + i];
        int ld = p >> 17;
        int q = atomicAdd(&cur[ld], 1);
        csr_src[q] = (int)(p & 0x1FFFFu);
    }
}

// ---------------- P4a: gemm1 chunk FIRST, then buckets [0, nPrim) ----------
__global__ __launch_bounds__(256) void k_csr_g1(const uintT* __restrict__ tmp,
                                                const int* __restrict__ bstart,
                                                const int* __restrict__ totals,
                                                int* __restrict__ rowptr,
                                                int* __restrict__ csr_src,
                                                int N,
                                                const float* __restrict__ A,
                                                const ushortT* __restrict__ Bt,
                                                ucharT* __restrict__ h1i,
                                                float* __restrict__ s1cc,
                                                float* __restrict__ s1d,
                                                int M, int nPrim, int slabBase) {
    __shared__ int cnt[128];
    __shared__ int cur[128];
    __shared__ int wtot;
    int nG = gridDim.x - nPrim;
    if (blockIdx.x < nG) {
        int wave = threadIdx.x >> 6;
        int slab = slabBase + blockIdx.x * 4 + wave;
        dev_gemm1(slab, A, Bt, h1i, s1cc, s1d, M);
        return;
    }
    dev_csr(blockIdx.x - nG, tmp, bstart, totals, rowptr, csr_src, N,
            cnt, cur, &wtot);
}

// ---------------- layer-1 aggregation worker (2 nodes/wave) -----------------
struct Edge1 {
    float2 svc;       // (score_head, row scale)
    uint4 v;
    int si;
};

static __device__ __forceinline__ void ldi1(Edge1& S, int j, int endm1,
                                            const int* __restrict__ csr_src) {
    int jj = j < endm1 ? j : endm1;
    S.si = csr_src[jj];
}

static __device__ __forceinline__ void ldv1(Edge1& S, int j, int end,
                                            const float2* __restrict__ sc2,
                                            const ucharT* __restrict__ hb, int head) {
    if (j < end) {
        int s = S.si;
        S.svc = sc2[((size_t)s << 3) + head];
        S.v = *(const uint4*)(hb + ((size_t)s << 8));
    }
}

static __device__ __forceinline__ void ac1(const Edge1& S, float sdn,
                                           float2v* A, float& l, float& sps) {
    float p = exp2f(lrelu(S.svc.x + sdn));   // scores pre-scaled by log2e
    l += p;
    float ps = p * S.svc.y;
    sps += ps;
    float2v p2 = {ps, ps};
    uintT w;
    w = S.v.x;
    A[0] += p2 * (float2v){ub(w, 0), ub(w, 1)};
    A[1] += p2 * (float2v){ub(w, 2), ub(w, 3)};
    w = S.v.y;
    A[2] += p2 * (float2v){ub(w, 0), ub(w, 1)};
    A[3] += p2 * (float2v){ub(w, 2), ub(w, 3)};
    w = S.v.z;
    A[4] += p2 * (float2v){ub(w, 0), ub(w, 1)};
    A[5] += p2 * (float2v){ub(w, 2), ub(w, 3)};
    w = S.v.w;
    A[6] += p2 * (float2v){ub(w, 0), ub(w, 1)};
    A[7] += p2 * (float2v){ub(w, 2), ub(w, 3)};
}

static __device__ __forceinline__ void dev_agg1_pair(int n0, int NN,
                                                     const ucharT* __restrict__ h1i,
                                                     const float* __restrict__ s1cc,
                                                     const float* __restrict__ s1d,
                                                     const int* __restrict__ rowptr,
                                                     const int* __restrict__ csr_src,
                                                     const float* __restrict__ b1,
                                                     ushortT* __restrict__ out1) {
    int lane = threadIdx.x & 63;
    int half = lane >> 5;
    int n = n0 + half;
    bool act = n < NN;
    int l32 = lane & 31;
    int g = l32 >> 4;            // 2 edge slots per half
    int cl = l32 & 15;           // 16 channels each
    int head = cl >> 1;
    int beg = 0, end = 0;
    if (act) {
        beg = rowptr[n];
        end = rowptr[n + 1];
    }
    float sdn = act ? s1d[(size_t)n * 8 + head] : 0.f;
    const ucharT* hb = h1i + cl * 16;
    const float2* sc2 = (const float2*)s1cc;
    float2v A[8];
    #pragma unroll
    for (int k = 0; k < 8; ++k) A[k] = (float2v){0.f, 0.f};
    float l = 0.f, sps = 0.f;
    int i0 = beg + g;
    if (i0 < end) {
        int endm1 = end - 1;
        Edge1 S0, S1, S2;
        S0.svc = S1.svc = S2.svc = make_float2(0.f, 0.f);
        S0.v = S1.v = S2.v = make_uint4(0u, 0u, 0u, 0u);
        ldi1(S0, i0, endm1, csr_src);
        ldi1(S1, i0 + 2, endm1, csr_src);
        ldi1(S2, i0 + 4, endm1, csr_src);
        ldv1(S0, i0, end, sc2, hb, head);
        ldv1(S1, i0 + 2, end, sc2, hb, head);
        ldv1(S2, i0 + 4, end, sc2, hb, head);
        ldi1(S0, i0 + 6, endm1, csr_src);
        ldi1(S1, i0 + 8, endm1, csr_src);
        ldi1(S2, i0 + 10, endm1, csr_src);
        for (int idx = i0; idx < end; idx += 6) {
            ac1(S0, sdn, A, l, sps);
            ldv1(S0, idx + 6, end, sc2, hb, head);
            ldi1(S0, idx + 12, endm1, csr_src);
            if (idx + 2 < end) {
                ac1(S1, sdn, A, l, sps);
                ldv1(S1, idx + 8, end, sc2, hb, head);
                ldi1(S1, idx + 14, endm1, csr_src);
            }
            if (idx + 4 < end) {
                ac1(S2, sdn, A, l, sps);
                ldv1(S2, idx + 10, end, sc2, hb, head);
                ldi1(S2, idx + 16, endm1, csr_src);
            }
        }
    }
    // reduce across the 2 slots (xor-16 stays inside the 32-lane half)
    l += __shfl_xor(l, 16, 64);
    sps += __shfl_xor(sps, 16, 64);
    #pragma unroll
    for (int k = 0; k < 8; ++k) {
        A[k].x += __shfl_xor(A[k].x, 16, 64);
        A[k].y += __shfl_xor(A[k].y, 16, 64);
    }
    if (g == 0 && act) {
        float inv = 1.f / l;
        float adj = 128.f * sps;            // undo the uint8 bias
        const float4 bb0 = *(const float4*)(b1 + cl * 16);
        const float4 bb1 = *(const float4*)(b1 + cl * 16 + 4);
        const float4 bb2 = *(const float4*)(b1 + cl * 16 + 8);
        const float4 bb3 = *(const float4*)(b1 + cl * 16 + 12);
        float bbf[16] = {bb0.x, bb0.y, bb0.z, bb0.w, bb1.x, bb1.y, bb1.z, bb1.w,
                         bb2.x, bb2.y, bb2.z, bb2.w, bb3.x, bb3.y, bb3.z, bb3.w};
        uintT o[8];
        #pragma unroll
        for (int k = 0; k < 8; ++k) {
            float x0 = fmaxf((A[k].x - adj) * inv + bbf[2 * k], 0.f);
            float x1 = fmaxf((A[k].y - adj) * inv + bbf[2 * k + 1], 0.f);
            o[k] = pk(x0, x1);
        }
        *(uint4*)(out1 + (size_t)n * 256 + cl * 16) =
            make_uint4(o[0], o[1], o[2], o[3]);
        *(uint4*)(out1 + (size_t)n * 256 + cl * 16 + 8) =
            make_uint4(o[4], o[5], o[6], o[7]);
    }
}

// ---------------- fused: P4b (buckets >= halfB) ∥ agg1 nodes [0, H) --------
__global__ __launch_bounds__(256) void k_csr_agg1(const uintT* __restrict__ tmp,
                                                  const int* __restrict__ bstart,
                                                  const int* __restrict__ totals,
                                                  int* __restrict__ rowptr,
                                                  int* __restrict__ csr_src,
                                                  int N, int halfB, int nP4,
                                                  const ucharT* __restrict__ h1i,
                                                  const float* __restrict__ s1cc,
                                                  const float* __restrict__ s1d,
                                                  const float* __restrict__ b1,
                                                  ushortT* __restrict__ out1, int H) {
    __shared__ int cnt[128];
    __shared__ int cur[128];
    __shared__ int wtot;
    if (blockIdx.x < nP4) {
        dev_csr(halfB + blockIdx.x, tmp, bstart, totals, rowptr, csr_src, N,
                cnt, cur, &wtot);
        return;
    }
    int n0 = (blockIdx.x - nP4) * 8 + (threadIdx.x >> 6) * 2;
    if (n0 >= H) return;
    dev_agg1_pair(n0, H, h1i, s1cc, s1d, rowptr, csr_src, b1, out1);
}

// ---------------- fused: gemm2 rows [0, H) FIRST, then agg1 nodes [H, N) ---
__global__ __launch_bounds__(256) void k_agg1_g2(const ucharT* __restrict__ h1i,
                                                 const float* __restrict__ s1cc,
                                                 const float* __restrict__ s1d,
                                                 const int* __restrict__ rowptr,
                                                 const int* __restrict__ csr_src,
                                                 const float* __restrict__ b1,
                                                 ushortT* __restrict__ out1,
                                                 int base, int N, int nAgg,
                                                 const ushortT* __restrict__ X,
                                                 const ushortT* __restrict__ Bt2,
                                                 const float* __restrict__ a2s,
                                                 const float* __restrict__ a2d,
                                                 ucharT* __restrict__ h2i,
                                                 float* __restrict__ s2d, int MG2) {
    int nG2 = gridDim.x - nAgg;
    if (blockIdx.x < nG2) {
        int wave = threadIdx.x >> 6;
        int slab = blockIdx.x * 4 + wave;
        dev_gemm2(slab, X, Bt2, a2s, a2d, h2i, s2d, MG2);
        return;
    }
    int n0 = base + (blockIdx.x - nG2) * 8 + (threadIdx.x >> 6) * 2;
    if (n0 >= N) return;
    dev_agg1_pair(n0, N, h1i, s1cc, s1d, rowptr, csr_src, b1, out1);
}

// ---------------- GEMM2 remainder: rows [H, N) -----------------------------
__global__ __launch_bounds__(256) void k_gemm2(const ushortT* __restrict__ X,
                                               const ushortT* __restrict__ Bt,
                                               const float* __restrict__ a2s,
                                               const float* __restrict__ a2d,
                                               ucharT* __restrict__ h2i,
                                               float* __restrict__ s2d,
                                               int slabBase, int M) {
    int wave = threadIdx.x >> 6;
    int slab = slabBase + blockIdx.x * 4 + wave;
    dev_gemm2(slab, X, Bt, a2s, a2d, h2i, s2d, M);
}

// ---------------- layer-2 aggregation + log_softmax (2 nodes/wave) ---------
// Per 32-lane half: one node, 3 slots x 10 ch-lanes (4 int8 ch each).
struct Edge2 {
    float2 svc;       // (score_src, row scale)
    uintT v;
    int si;
};

static __device__ __forceinline__ void ldi2(Edge2& S, int j, int endm1,
                                            const int* __restrict__ csr_src) {
    int jj = j < endm1 ? j : endm1;
    S.si = csr_src[jj];
}

static __device__ __forceinline__ void ldv2(Edge2& S, int j, int end,
                                            const ucharT* __restrict__ h2i, int cl) {
    if (j < end) {
        const ucharT* hr = h2i + (size_t)S.si * 64;
        S.v = *(const uintT*)(hr + cl * 4);
        S.svc = *(const float2*)(hr + 40);
    }
}

static __device__ __forceinline__ void ac2(const Edge2& S, float sdn,
                                           float2v& A01, float2v& A23,
                                           float& l, float& sps) {
    float p = exp2f(lrelu(S.svc.x + sdn));   // pre-scaled scores
    l += p;
    float ps = p * S.svc.y;
    sps += ps;
    float2v p2 = {ps, ps};
    A01 += p2 * (float2v){ub(S.v, 0), ub(S.v, 1)};
    A23 += p2 * (float2v){ub(S.v, 2), ub(S.v, 3)};
}

__global__ __launch_bounds__(256) void k_agg2lsm(const ucharT* __restrict__ h2i,
                                                 const float* __restrict__ sd,
                                                 const int* __restrict__ rowptr,
                                                 const int* __restrict__ csr_src,
                                                 const float* __restrict__ b2,
                                                 float* __restrict__ out, int N) {
    int lane = threadIdx.x & 63;
    int half = lane >> 5;
    int l32 = lane & 31;
    int n = blockIdx.x * 8 + (threadIdx.x >> 6) * 2 + half;
    bool act = n < N;
    int el = l32 / 10;           // 0..3 (l32 30,31 idle)
    int cl = l32 - el * 10;      // 10 ch-lanes x 4 int8 channels
    int beg = 0, end = 0;
    if (act) {
        beg = rowptr[n];
        end = rowptr[n + 1];
    }
    float sdn = act ? sd[n] : 0.f;
    float2v A01 = (float2v){0.f, 0.f}, A23 = (float2v){0.f, 0.f};
    float l = 0.f, sps = 0.f;
    if (el < 3) {
        int i0 = beg + el;
        if (i0 < end) {
            int endm1 = end - 1;
            Edge2 S0, S1, S2;
            S0.svc = S1.svc = S2.svc = make_float2(0.f, 0.f);
            S0.v = S1.v = S2.v = 0u;
            ldi2(S0, i0, endm1, csr_src);
            ldi2(S1, i0 + 3, endm1, csr_src);
            ldi2(S2, i0 + 6, endm1, csr_src);
            ldv2(S0, i0, end, h2i, cl);
            ldv2(S1, i0 + 3, end, h2i, cl);
            ldv2(S2, i0 + 6, end, h2i, cl);
            ldi2(S0, i0 + 9, endm1, csr_src);
            ldi2(S1, i0 + 12, endm1, csr_src);
            ldi2(S2, i0 + 15, endm1, csr_src);
            for (int idx = i0; idx < end; idx += 9) {
                ac2(S0, sdn, A01, A23, l, sps);
                ldv2(S0, idx + 9, end, h2i, cl);
                ldi2(S0, idx + 18, endm1, csr_src);
                if (idx + 3 < end) {
                    ac2(S1, sdn, A01, A23, l, sps);
                    ldv2(S1, idx + 12, end, h2i, cl);
                    ldi2(S1, idx + 21, endm1, csr_src);
                }
                if (idx + 6 < end) {
                    ac2(S2, sdn, A01, A23, l, sps);
                    ldv2(S2, idx + 15, end, h2i, cl);
                    ldi2(S2, idx + 24, endm1, csr_src);
                }
            }
        }
    }
    float a0 = A01.x, a1 = A01.y, a2 = A23.x, a3 = A23.y;
    // fold slots 1,2 -> slot 0 within each half (valid on el==0 lanes)
    int base = lane & 32;
    int f1 = base + cl + 10, f2 = base + cl + 20;
    a0 += __shfl(a0, f1, 64) + __shfl(a0, f2, 64);
    a1 += __shfl(a1, f1, 64) + __shfl(a1, f2, 64);
    a2 += __shfl(a2, f1, 64) + __shfl(a2, f2, 64);
    a3 += __shfl(a3, f1, 64) + __shfl(a3, f2, 64);
    l  += __shfl(l, f1, 64) + __shfl(l, f2, 64);
    sps += __shfl(sps, f1, 64) + __shfl(sps, f2, 64);
    float inv = 1.f / l;
    float adj = 128.f * sps;            // undo the uint8 bias
    float4 bb = *(const float4*)(b2 + cl * 4);
    float o0 = (a0 - adj) * inv + bb.x;
    float o1 = (a1 - adj) * inv + bb.y;
    float o2 = (a2 - adj) * inv + bb.z;
    float o3 = (a3 - adj) * inv + bb.w;
    bool valid = (el == 0);             // l32 < 10
    float lm = valid ? fmaxf(fmaxf(o0, o1), fmaxf(o2, o3)) : -INFINITY;
    #pragma unroll
    for (int off = 16; off; off >>= 1) lm = fmaxf(lm, __shfl_xor(lm, off, 64));
    float le = valid
        ? __expf(o0 - lm) + __expf(o1 - lm) + __expf(o2 - lm) + __expf(o3 - lm)
        : 0.f;
    #pragma unroll
    for (int off = 16; off; off >>= 1) le += __shfl_xor(le, off, 64);
    float ls = lm + logf(le);
    if (valid && act) {
        float4 w = make_float4(o0 - ls, o1 - ls, o2 - ls, o3 - ls);
        *(float4*)(out + (size_t)n * 40 + cl * 4) = w;
    }
}

// ---------------------------------------------------------------------------
extern "C" void kernel_launch(void* const* d_in, const int* in_sizes, int n_in,
                              void* d_out, int out_size, void* d_ws, size_t ws_size,
                              hipStream_t stream) {
    const float* x   = (const float*)d_in[0];
    const int*   ei  = (const int*)d_in[1];
    const float* W1  = (const float*)d_in[2];
    const float* a1s = (const float*)d_in[3];
    const float* a1d = (const float*)d_in[4];
    const float* b1  = (const float*)d_in[5];
    const float* W2  = (const float*)d_in[6];
    const float* a2s = (const float*)d_in[7];
    const float* a2d = (const float*)d_in[8];
    const float* b2  = (const float*)d_in[9];
    float* out = (float*)d_out;

    const int N = in_sizes[0] / 128;   // 100000
    const int E = in_sizes[1] / 2;     // 1600000
    const int ET = E + N;
    const int NBUCK = (N + 127) >> 7;              // 782
    const int NB1 = (E + EPB - 1) / EPB;           // 391

    // ---- workspace layout ----
    char* w = (char*)d_ws;
    ucharT* h1i = (ucharT*)w;                             // N*256 u8 (25.6 MB)
    ushortT* out1b = (ushortT*)(w + (size_t)N * 256);     // N*256 bf16 (51.2 MB)
    int* i_row = (int*)(w + (size_t)N * 768);             // N+16 ints
    float* s1cc = (float*)(w + (size_t)N * 768 + ((size_t)N + 16) * 4); // N*16 f32
    float* s1d = s1cc + (size_t)N * 16;                   // N*8 f32
    int* i_cnt = (int*)(s1d + (size_t)N * 8);             // NB1*NBUCK
    int* i_tot = i_cnt + (size_t)NB1 * NBUCK;             // NBUCK+2
    int* i_bst = i_tot + NBUCK + 2;                       // NBUCK+2
    // i_tmp aligned UP to 64B so the h2i overlay starts exactly at i_tmp.
    uintT* i_tmp = (uintT*)(((uintptr_t)(i_bst + NBUCK + 2) + 63) &
                            ~(uintptr_t)63);              // E packed pairs
    int* i_csr = (int*)(i_tmp + E);                       // ET ints
    ushortT* W1t = (ushortT*)(i_csr + ET);                // 272*128 bf16
    ushortT* W2t = W1t + 272 * 128;                       // 64*256 bf16
    // layer-2 overlays (dead after P4 / P3):
    //   h2i: N*64 B == E*4 B, exactly over i_tmp (64B-aligned).
    //   s2d (N f32) over i_cnt (dead after P3).
    ucharT* h2i = (ucharT*)i_tmp;
    float* s2d = (float*)i_cnt;

    const int nbG = (N / 16 + 3) / 4;            // gemm1 blocks (4 waves x 16 rows)
    const int CH  = (nbG + 2) / 3;               // gemm1 chunk (blocks)
    const int halfB = (NBUCK * 9) >> 4;          // 439 (K1/K2 balance)
    const int H = halfB << 7;                    // 56192 nodes in first part
    const int nP4b = NBUCK - halfB;              // 343
    const int nAgg1a = (H + 7) / 8;              // agg1 pair blocks, first part
    const int nAgg1b = (N - H + 7) / 8;          // agg1 pair blocks, tail
    const int g2aSlabs = H / 16;                 // 3512 (H multiple of 16)
    const int g2aBlocks = g2aSlabs / 4;          // 878
    const int nSlab = (N + 15) / 16;             // 6250
    const int g2bBlocks = (nSlab - g2aSlabs + 3) / 4;   // 685
    const int nb8 = (N + 7) / 8;                 // agg2 blocks (8 nodes each)

    // ---- L0: weight prep ----
    k_prep<<<PREP_BLOCKS, 256, 0, stream>>>(W1, W2, a1s, a1d, W1t, W2t);
    // ---- P1: gemm1 chunk 0 (first) ∥ bucket histogram ----
    k_cnt_g1<<<CH + NB1, 256, 0, stream>>>(ei, E, i_cnt, NBUCK,
                                           x, W1t, h1i, s1cc, s1d,
                                           N, NB1, 0);
    // ---- P2: per-bucket scan across blocks ----
    k_scan_cols<<<NBUCK, 256, 0, stream>>>(i_cnt, i_tot, NB1, NBUCK);
    // ---- P3: gemm1 chunk 1 (first) ∥ bucket-contiguous placement ----
    k_place_g1<<<CH + NB1, 256, 0, stream>>>(ei, E, i_cnt, i_tot, i_bst, i_tmp, NBUCK,
                                             x, W1t, h1i, s1cc, s1d,
                                             N, NB1, CH * 4);
    // ---- P4a: gemm1 chunk 2 (first) ∥ CSR finalize buckets [0, halfB) ----
    k_csr_g1<<<CH + halfB, 256, 0, stream>>>(i_tmp, i_bst, i_tot, i_row, i_csr, N,
                                             x, W1t, h1i, s1cc, s1d,
                                             N, halfB, CH * 8);
    // ---- P4b ∥ agg1 nodes [0, H) ----
    k_csr_agg1<<<nP4b + nAgg1a, 256, 0, stream>>>(i_tmp, i_bst, i_tot, i_row, i_csr,
                                                  N, halfB, nP4b,
                                                  h1i, s1cc, s1d, b1, out1b, H);
    // ---- gemm2 rows [0, H) (first) ∥ agg1 tail nodes [H, N) ----
    k_agg1_g2<<<g2aBlocks + nAgg1b, 256, 0, stream>>>(h1i, s1cc, s1d, i_row, i_csr,
                                                      b1, out1b, H, N, nAgg1b,
                                                      out1b, W2t, a2s, a2d,
                                                      h2i, s2d, H);
    // ---- gemm2 remainder rows [H, N) ----
    k_gemm2<<<g2bBlocks, 256, 0, stream>>>(out1b, W2t, a2s, a2d, h2i, s2d,
                                           g2aSlabs, N);
    // ---- layer-2 aggregation + log_softmax ----
    k_agg2lsm<<<nb8, 256, 0, stream>>>(h2i, s2d, i_row, i_csr, b2, out, N);
}